// Round 1
// baseline (3235.826 us; speedup 1.0000x reference)
//
#include <hip/hip_runtime.h>
#include <hip/hip_bf16.h>
#include <cstdint>
#include <cstddef>

#define N_NODES 50000
#define N_EDGES 800000
#define CH 512

typedef __attribute__((ext_vector_type(8))) short bf16x8;
typedef __attribute__((ext_vector_type(4))) float f32x4;

__device__ inline unsigned short f2b(float f) {
    __hip_bfloat16 h = __float2bfloat16(f);
    return *(unsigned short*)&h;
}
__device__ inline float blo(unsigned int u) {  // low 16 bits as bf16 -> f32
    union { unsigned int i; float f; } v; v.i = u << 16; return v.f;
}
__device__ inline float bhi(unsigned int u) {  // high 16 bits as bf16 -> f32
    union { unsigned int i; float f; } v; v.i = u & 0xffff0000u; return v.f;
}
__device__ inline unsigned int pack2(unsigned short a, unsigned short b) {
    return (unsigned)a | ((unsigned)b << 16);
}

// ---------------- CSR build ----------------

__global__ __launch_bounds__(256) void count_col(const int* __restrict__ col, int* __restrict__ cnt) {
    int e = blockIdx.x * 256 + threadIdx.x;
    if (e < N_EDGES) atomicAdd(&cnt[col[e]], 1);
}

__global__ __launch_bounds__(256) void make_dinv(const int* __restrict__ cnt, float* __restrict__ dinv) {
    int i = blockIdx.x * 256 + threadIdx.x;
    if (i < N_NODES) dinv[i] = rsqrtf((float)(cnt[i] + 1));  // +1 self loop
}

__global__ __launch_bounds__(1024) void scan_offsets(const int* __restrict__ cnt, int* __restrict__ offs) {
    __shared__ int wsum[16];
    __shared__ int s_carry;
    int tid = threadIdx.x;
    int lane = tid & 63, wid = tid >> 6;
    if (tid == 0) s_carry = 0;
    __syncthreads();
    const int n = N_NODES;
    for (int c0 = 0; c0 < n; c0 += 1024) {
        int i = c0 + tid;
        int v = (i < n) ? cnt[i] : 0;
        int incl = v;
        #pragma unroll
        for (int d = 1; d < 64; d <<= 1) {
            int t = __shfl_up(incl, d, 64);
            if (lane >= d) incl += t;
        }
        if (lane == 63) wsum[wid] = incl;
        __syncthreads();
        int wbase = 0;
        for (int w = 0; w < wid; ++w) wbase += wsum[w];
        int excl = s_carry + wbase + incl - v;
        if (i < n) offs[i] = excl;
        int ctot = wbase + incl;
        __syncthreads();
        if (tid == 1023) s_carry += ctot;
        __syncthreads();
    }
    if (tid == 0) offs[n] = s_carry;
}

__global__ __launch_bounds__(256) void fill_csr(const int* __restrict__ edges,
                                                const int* __restrict__ offs,
                                                int* __restrict__ cursor,
                                                const float* __restrict__ dinv,
                                                int* __restrict__ srcs,
                                                float* __restrict__ enorm) {
    int e = blockIdx.x * 256 + threadIdx.x;
    if (e >= N_EDGES) return;
    int r = edges[e];            // source
    int c = edges[N_EDGES + e];  // destination
    int p = offs[c] + atomicAdd(&cursor[c], 1);
    srcs[p] = r;
    enorm[p] = dinv[r] * dinv[c];
}

// ---------------- converters ----------------

__global__ __launch_bounds__(256) void convert_x_bf16(const float* __restrict__ x, unsigned short* __restrict__ xb) {
    int i8 = blockIdx.x * 256 + threadIdx.x;  // 8 floats per thread
    const float4* x4 = (const float4*)x;
    float4 a = x4[2 * i8], b = x4[2 * i8 + 1];
    unsigned int o[4];
    o[0] = pack2(f2b(a.x), f2b(a.y));
    o[1] = pack2(f2b(a.z), f2b(a.w));
    o[2] = pack2(f2b(b.x), f2b(b.y));
    o[3] = pack2(f2b(b.z), f2b(b.w));
    ((uint4*)xb)[i8] = make_uint4(o[0], o[1], o[2], o[3]);
}

// Wt[n][k] = bf16(W[k][n])
__global__ __launch_bounds__(256) void convert_w_t(const float* __restrict__ W, unsigned short* __restrict__ Wt) {
    int id = blockIdx.x * 256 + threadIdx.x;
    int k = id >> 9, n = id & 511;
    Wt[(size_t)n * 512 + k] = f2b(W[(size_t)k * 512 + n]);
}

// Split W into hi/lo bf16, transposed n-major: Wth[n][k] + Wtl[n][k] ~= W[k][n] (fp32)
__global__ __launch_bounds__(256) void convert_w_t_split(const float* __restrict__ W,
                                                         unsigned short* __restrict__ Wth,
                                                         unsigned short* __restrict__ Wtl) {
    int id = blockIdx.x * 256 + threadIdx.x;
    int k = id >> 9, n = id & 511;
    float f = W[(size_t)k * 512 + n];
    unsigned short hb = f2b(f);  // RTN
    union { unsigned int u; float ff; } t; t.u = (unsigned)hb << 16;
    float lo = f - t.ff;
    Wth[(size_t)n * 512 + k] = hb;
    Wtl[(size_t)n * 512 + k] = f2b(lo);
}

// ---------------- fp32 propagation (conv1): unroll-4 gather ----------------

__global__ __launch_bounds__(128) void propagate(const float* __restrict__ h, float* __restrict__ out,
                                                 const int* __restrict__ offs,
                                                 const int* __restrict__ srcs,
                                                 const float* __restrict__ enorm,
                                                 const float* __restrict__ dinv) {
    int node = blockIdx.x;
    int t = threadIdx.x;  // 128 threads * float4 = 512 channels
    const float4* h4 = (const float4*)h;
    float di = dinv[node];
    float w0 = di * di;
    float4 v = h4[(size_t)node * 128 + t];
    float4 acc = make_float4(v.x * w0, v.y * w0, v.z * w0, v.w * w0);
    int e0 = offs[node], e1 = offs[node + 1];
    int e = e0;
    int eu = e0 + ((e1 - e0) & ~3);
    for (; e < eu; e += 4) {
        int s0 = srcs[e], s1 = srcs[e + 1], s2 = srcs[e + 2], s3 = srcs[e + 3];
        float wa = enorm[e], wb = enorm[e + 1], wc = enorm[e + 2], wd = enorm[e + 3];
        float4 u0 = h4[(size_t)s0 * 128 + t];
        float4 u1 = h4[(size_t)s1 * 128 + t];
        float4 u2 = h4[(size_t)s2 * 128 + t];
        float4 u3 = h4[(size_t)s3 * 128 + t];
        acc.x += u0.x * wa; acc.y += u0.y * wa; acc.z += u0.z * wa; acc.w += u0.w * wa;
        acc.x += u1.x * wb; acc.y += u1.y * wb; acc.z += u1.z * wb; acc.w += u1.w * wb;
        acc.x += u2.x * wc; acc.y += u2.y * wc; acc.z += u2.z * wc; acc.w += u2.w * wc;
        acc.x += u3.x * wd; acc.y += u3.y * wd; acc.z += u3.z * wd; acc.w += u3.w * wd;
    }
    for (; e < e1; ++e) {
        int s = srcs[e];
        float w = enorm[e];
        float4 u = h4[(size_t)s * 128 + t];
        acc.x += u.x * w; acc.y += u.y * w; acc.z += u.z * w; acc.w += u.w * w;
    }
    ((float4*)out)[(size_t)node * 128 + t] = acc;
}

// ---------------- bf16 propagation (conv2): wave per node, fp32 accum ----------------

__global__ __launch_bounds__(128) void propagate_bf16(const unsigned short* __restrict__ hb,
                                                      unsigned short* __restrict__ outb,
                                                      const int* __restrict__ offs,
                                                      const int* __restrict__ srcs,
                                                      const float* __restrict__ enorm,
                                                      const float* __restrict__ dinv) {
    int node = blockIdx.x * 2 + (threadIdx.x >> 6);
    int lane = threadIdx.x & 63;  // lane handles 8 channels (16 B)
    const uint4* h16 = (const uint4*)hb;  // 64 uint4 per row
    float di = dinv[node];
    float w0 = di * di;
    float acc[8];
    uint4 sv = h16[(size_t)node * 64 + lane];
    acc[0] = blo(sv.x) * w0; acc[1] = bhi(sv.x) * w0;
    acc[2] = blo(sv.y) * w0; acc[3] = bhi(sv.y) * w0;
    acc[4] = blo(sv.z) * w0; acc[5] = bhi(sv.z) * w0;
    acc[6] = blo(sv.w) * w0; acc[7] = bhi(sv.w) * w0;
    int e0 = offs[node], e1 = offs[node + 1];
    int e = e0;
    int eu = e0 + ((e1 - e0) & ~3);
    for (; e < eu; e += 4) {
        int s0 = srcs[e], s1 = srcs[e + 1], s2 = srcs[e + 2], s3 = srcs[e + 3];
        float wa = enorm[e], wb = enorm[e + 1], wc = enorm[e + 2], wd = enorm[e + 3];
        uint4 u0 = h16[(size_t)s0 * 64 + lane];
        uint4 u1 = h16[(size_t)s1 * 64 + lane];
        uint4 u2 = h16[(size_t)s2 * 64 + lane];
        uint4 u3 = h16[(size_t)s3 * 64 + lane];
        acc[0] += blo(u0.x) * wa; acc[1] += bhi(u0.x) * wa;
        acc[2] += blo(u0.y) * wa; acc[3] += bhi(u0.y) * wa;
        acc[4] += blo(u0.z) * wa; acc[5] += bhi(u0.z) * wa;
        acc[6] += blo(u0.w) * wa; acc[7] += bhi(u0.w) * wa;
        acc[0] += blo(u1.x) * wb; acc[1] += bhi(u1.x) * wb;
        acc[2] += blo(u1.y) * wb; acc[3] += bhi(u1.y) * wb;
        acc[4] += blo(u1.z) * wb; acc[5] += bhi(u1.z) * wb;
        acc[6] += blo(u1.w) * wb; acc[7] += bhi(u1.w) * wb;
        acc[0] += blo(u2.x) * wc; acc[1] += bhi(u2.x) * wc;
        acc[2] += blo(u2.y) * wc; acc[3] += bhi(u2.y) * wc;
        acc[4] += blo(u2.z) * wc; acc[5] += bhi(u2.z) * wc;
        acc[6] += blo(u2.w) * wc; acc[7] += bhi(u2.w) * wc;
        acc[0] += blo(u3.x) * wd; acc[1] += bhi(u3.x) * wd;
        acc[2] += blo(u3.y) * wd; acc[3] += bhi(u3.y) * wd;
        acc[4] += blo(u3.z) * wd; acc[5] += bhi(u3.z) * wd;
        acc[6] += blo(u3.w) * wd; acc[7] += bhi(u3.w) * wd;
    }
    for (; e < e1; ++e) {
        int s = srcs[e];
        float w = enorm[e];
        uint4 u = h16[(size_t)s * 64 + lane];
        acc[0] += blo(u.x) * w; acc[1] += bhi(u.x) * w;
        acc[2] += blo(u.y) * w; acc[3] += bhi(u.y) * w;
        acc[4] += blo(u.z) * w; acc[5] += bhi(u.z) * w;
        acc[6] += blo(u.w) * w; acc[7] += bhi(u.w) * w;
    }
    unsigned int o0 = pack2(f2b(acc[0]), f2b(acc[1]));
    unsigned int o1 = pack2(f2b(acc[2]), f2b(acc[3]));
    unsigned int o2 = pack2(f2b(acc[4]), f2b(acc[5]));
    unsigned int o3 = pack2(f2b(acc[6]), f2b(acc[7]));
    ((uint4*)outb)[(size_t)node * 64 + lane] = make_uint4(o0, o1, o2, o3);
}

// ---------------- bf16 MFMA GEMM (conv2): C[M,512] = Ab @ Wt^T + bias ----------------
// Block: 256 thr = 4 waves (2x2), tile BM2=128 x BN2=64, BK2=32.

#define BM2 128
#define BN2 64
#define BK2 32
#define LDP 40  // LDS row pitch in shorts (80 B -> 2-way bank aliasing only)

__global__ __launch_bounds__(256) void gemm_bf16(const unsigned short* __restrict__ Ab,
                                                 const unsigned short* __restrict__ Wt,
                                                 const float* __restrict__ bias,
                                                 float* __restrict__ C) {
    __shared__ short Alds[BM2 * LDP];
    __shared__ short Blds[BN2 * LDP];
    int tid = threadIdx.x;
    int lane = tid & 63;
    int wid = tid >> 6;
    int wm = wid & 1;   // 0/1 -> 64-row half
    int wn = wid >> 1;  // 0/1 -> 32-col half
    int bm = blockIdx.x * BM2;
    int bn = blockIdx.y * BN2;

    f32x4 acc[4][2] = {};

    int arow0 = tid >> 2, aq = tid & 3;
    int brow = tid >> 2, bq = tid & 3;

    for (int k0 = 0; k0 < CH; k0 += BK2) {
        #pragma unroll
        for (int h = 0; h < 2; ++h) {
            int row = arow0 + h * 64;
            int gr = bm + row;
            uint4 v = make_uint4(0u, 0u, 0u, 0u);
            if (gr < N_NODES) v = *(const uint4*)&Ab[(size_t)gr * CH + k0 + aq * 8];
            *(uint4*)&Alds[row * LDP + aq * 8] = v;
        }
        {
            uint4 v = *(const uint4*)&Wt[(size_t)(bn + brow) * CH + k0 + bq * 8];
            *(uint4*)&Blds[brow * LDP + bq * 8] = v;
        }
        __syncthreads();

        bf16x8 af[4], bf[2];
        #pragma unroll
        for (int mt = 0; mt < 4; ++mt)
            af[mt] = *(const bf16x8*)&Alds[(wm * 64 + mt * 16 + (lane & 15)) * LDP + (lane >> 4) * 8];
        #pragma unroll
        for (int nt = 0; nt < 2; ++nt)
            bf[nt] = *(const bf16x8*)&Blds[(wn * 32 + nt * 16 + (lane & 15)) * LDP + (lane >> 4) * 8];
        #pragma unroll
        for (int mt = 0; mt < 4; ++mt)
            #pragma unroll
            for (int nt = 0; nt < 2; ++nt)
                acc[mt][nt] = __builtin_amdgcn_mfma_f32_16x16x32_bf16(af[mt], bf[nt], acc[mt][nt], 0, 0, 0);
        __syncthreads();
    }

    #pragma unroll
    for (int mt = 0; mt < 4; ++mt) {
        #pragma unroll
        for (int nt = 0; nt < 2; ++nt) {
            int col = bn + wn * 32 + nt * 16 + (lane & 15);
            float bv = bias[col];
            #pragma unroll
            for (int r = 0; r < 4; ++r) {
                int row = bm + wm * 64 + mt * 16 + (lane >> 4) * 4 + r;
                if (row < N_NODES) C[(size_t)row * CH + col] = acc[mt][nt][r] + bv;
            }
        }
    }
}

// ---------------- bf16x3 split MFMA GEMM (conv1): C = A(f32) @ W + bias ----------------
// A stays fp32 in memory; hi/lo bf16 split happens during LDS staging.
// C ~= A_hi@W_hi + A_lo@W_hi + A_hi@W_lo   (error ~2^-16 relative per product)

#define BM3 128
#define BN3 64
#define BK3 32
#define LDP3 40

__global__ __launch_bounds__(256) void gemm_bf16x3(const float* __restrict__ A,
                                                   const unsigned short* __restrict__ Wth,
                                                   const unsigned short* __restrict__ Wtl,
                                                   const float* __restrict__ bias,
                                                   float* __restrict__ C) {
    __shared__ short Ah[BM3 * LDP3];
    __shared__ short Al[BM3 * LDP3];
    __shared__ short Bh[BN3 * LDP3];
    __shared__ short Bl[BN3 * LDP3];
    int tid = threadIdx.x;
    int lane = tid & 63;
    int wid = tid >> 6;
    int wm = wid & 1;
    int wn = wid >> 1;
    int bm = blockIdx.x * BM3;
    int bn = blockIdx.y * BN3;

    f32x4 acc[4][2] = {};

    // A staging: 128 rows x 32 fp32 per step; thread t -> row t>>1, 16-float segment t&1
    int arow = tid >> 1, aseg = tid & 1;
    int ga = bm + arow;
    bool aval = ga < N_NODES;
    const float4* A4 = (const float4*)A;
    // B staging: 64 n-rows x 32 k bf16 per buffer; thread -> row tid>>2, 8-elem quad tid&3
    int brow = tid >> 2, bq = tid & 3;

    for (int k0 = 0; k0 < CH; k0 += BK3) {
        // ---- stage A, splitting fp32 -> hi/lo bf16 in registers ----
        {
            size_t base = (size_t)ga * 128 + (k0 >> 2) + aseg * 4;
            unsigned short h[16], l[16];
            #pragma unroll
            for (int v = 0; v < 4; ++v) {
                float4 f = aval ? A4[base + v] : make_float4(0.f, 0.f, 0.f, 0.f);
                float fs[4] = {f.x, f.y, f.z, f.w};
                #pragma unroll
                for (int j = 0; j < 4; ++j) {
                    unsigned short hb = f2b(fs[j]);       // RTN hi
                    union { unsigned int u; float ff; } t; t.u = (unsigned)hb << 16;
                    float lo = fs[j] - t.ff;              // exact remainder
                    h[v * 4 + j] = hb;
                    l[v * 4 + j] = f2b(lo);
                }
            }
            uint4 H0 = make_uint4(pack2(h[0], h[1]), pack2(h[2], h[3]), pack2(h[4], h[5]), pack2(h[6], h[7]));
            uint4 H1 = make_uint4(pack2(h[8], h[9]), pack2(h[10], h[11]), pack2(h[12], h[13]), pack2(h[14], h[15]));
            uint4 L0 = make_uint4(pack2(l[0], l[1]), pack2(l[2], l[3]), pack2(l[4], l[5]), pack2(l[6], l[7]));
            uint4 L1 = make_uint4(pack2(l[8], l[9]), pack2(l[10], l[11]), pack2(l[12], l[13]), pack2(l[14], l[15]));
            *(uint4*)&Ah[arow * LDP3 + aseg * 16] = H0;
            *(uint4*)&Ah[arow * LDP3 + aseg * 16 + 8] = H1;
            *(uint4*)&Al[arow * LDP3 + aseg * 16] = L0;
            *(uint4*)&Al[arow * LDP3 + aseg * 16 + 8] = L1;
        }
        // ---- stage B hi/lo ----
        *(uint4*)&Bh[brow * LDP3 + bq * 8] = *(const uint4*)&Wth[(size_t)(bn + brow) * CH + k0 + bq * 8];
        *(uint4*)&Bl[brow * LDP3 + bq * 8] = *(const uint4*)&Wtl[(size_t)(bn + brow) * CH + k0 + bq * 8];
        __syncthreads();

        bf16x8 afh[4], afl[4], bfh[2], bfl[2];
        #pragma unroll
        for (int mt = 0; mt < 4; ++mt) {
            int off = (wm * 64 + mt * 16 + (lane & 15)) * LDP3 + (lane >> 4) * 8;
            afh[mt] = *(const bf16x8*)&Ah[off];
            afl[mt] = *(const bf16x8*)&Al[off];
        }
        #pragma unroll
        for (int nt = 0; nt < 2; ++nt) {
            int off = (wn * 32 + nt * 16 + (lane & 15)) * LDP3 + (lane >> 4) * 8;
            bfh[nt] = *(const bf16x8*)&Bh[off];
            bfl[nt] = *(const bf16x8*)&Bl[off];
        }
        #pragma unroll
        for (int mt = 0; mt < 4; ++mt)
            #pragma unroll
            for (int nt = 0; nt < 2; ++nt) {
                acc[mt][nt] = __builtin_amdgcn_mfma_f32_16x16x32_bf16(afh[mt], bfh[nt], acc[mt][nt], 0, 0, 0);
                acc[mt][nt] = __builtin_amdgcn_mfma_f32_16x16x32_bf16(afl[mt], bfh[nt], acc[mt][nt], 0, 0, 0);
                acc[mt][nt] = __builtin_amdgcn_mfma_f32_16x16x32_bf16(afh[mt], bfl[nt], acc[mt][nt], 0, 0, 0);
            }
        __syncthreads();
    }

    #pragma unroll
    for (int mt = 0; mt < 4; ++mt) {
        #pragma unroll
        for (int nt = 0; nt < 2; ++nt) {
            int col = bn + wn * 32 + nt * 16 + (lane & 15);
            float bv = bias[col];
            #pragma unroll
            for (int r = 0; r < 4; ++r) {
                int row = bm + wm * 64 + mt * 16 + (lane >> 4) * 4 + r;
                if (row < N_NODES) C[(size_t)row * CH + col] = acc[mt][nt][r] + bv;
            }
        }
    }
}

// ---------------- Softmax (+argmax + top-2 gap suspects), one wave per row ----------------

#define GAP_THR 1.0e-2f

__global__ __launch_bounds__(256) void softmax_rows(const float* __restrict__ X, float* __restrict__ P,
                                                    float* __restrict__ preds,
                                                    int* __restrict__ susp_cnt,
                                                    int* __restrict__ susp_rows) {
    int row = blockIdx.x * 4 + (threadIdx.x >> 6);
    int lane = threadIdx.x & 63;
    if (row >= N_NODES) return;
    const float4* x4 = (const float4*)(X + (size_t)row * CH);
    float4 v0 = x4[lane];
    float4 v1 = x4[lane + 64];
    float vals[8] = {v0.x, v0.y, v0.z, v0.w, v1.x, v1.y, v1.z, v1.w};
    float m = vals[0];
    float m2 = -INFINITY;
    int mi = lane * 4;
    #pragma unroll
    for (int j = 1; j < 8; ++j) {
        int c = (j < 4) ? (lane * 4 + j) : (256 + lane * 4 + (j - 4));
        if (vals[j] > m) { m2 = m; m = vals[j]; mi = c; }
        else if (vals[j] > m2) { m2 = vals[j]; }
    }
    #pragma unroll
    for (int d = 32; d > 0; d >>= 1) {
        float om = __shfl_xor(m, d, 64);
        int oi = __shfl_xor(mi, d, 64);
        float om2 = __shfl_xor(m2, d, 64);
        if (om > m || (om == m && oi < mi)) {
            m2 = fmaxf(m, om2);
            m = om; mi = oi;
        } else {
            m2 = fmaxf(m2, om);
        }
    }
    float s = 0.f;
    float ex[8];
    #pragma unroll
    for (int j = 0; j < 8; ++j) { ex[j] = __expf(vals[j] - m); s += ex[j]; }
    #pragma unroll
    for (int d = 32; d > 0; d >>= 1) s += __shfl_xor(s, d, 64);
    float inv = 1.0f / s;
    float4 o0 = make_float4(ex[0] * inv, ex[1] * inv, ex[2] * inv, ex[3] * inv);
    float4 o1 = make_float4(ex[4] * inv, ex[5] * inv, ex[6] * inv, ex[7] * inv);
    float4* p4 = (float4*)(P + (size_t)row * CH);
    p4[lane] = o0;
    p4[lane + 64] = o1;
    if (preds != nullptr && lane == 0) {
        preds[row] = (float)mi;
        if (m - m2 < GAP_THR) {
            int p = atomicAdd(susp_cnt, 1);
            susp_rows[p] = row;
        }
    }
}

// ---------------- exact fp32 argmax fixup for suspect rows ----------------
// For each suspect row: recompute logits = A_row(f32) @ W + bias in fp32, rewrite preds.

__global__ __launch_bounds__(256) void fix_preds(const float* __restrict__ A, const float* __restrict__ W,
                                                 const float* __restrict__ bias,
                                                 const int* __restrict__ susp_cnt,
                                                 const int* __restrict__ susp_rows,
                                                 float* __restrict__ preds) {
    __shared__ float rowbuf[8][512];
    __shared__ float rbest[8][4];
    __shared__ int ridx[8][4];
    int cnt = *susp_cnt;
    if (cnt > N_NODES) cnt = N_NODES;
    int tid = threadIdx.x, lane = tid & 63, wid = tid >> 6;
    for (int base = blockIdx.x * 8; base < cnt; base += gridDim.x * 8) {
        int nr = min(8, cnt - base);
        __syncthreads();  // protect rowbuf reuse across sweep iterations
        for (int r = 0; r < nr; ++r) {
            int row = susp_rows[base + r];
            if (tid < 128) ((float4*)rowbuf[r])[tid] = ((const float4*)&A[(size_t)row * 512])[tid];
        }
        __syncthreads();
        float best[8]; int bidx[8];
        #pragma unroll
        for (int r = 0; r < 8; ++r) { best[r] = -INFINITY; bidx[r] = 0; }
        for (int cc = 0; cc < 2; ++cc) {
            int c = cc * 256 + tid;
            float bv = bias[c];
            float s[8];
            #pragma unroll
            for (int r = 0; r < 8; ++r) s[r] = bv;
            for (int k = 0; k < 512; ++k) {
                float w = W[(size_t)k * 512 + c];
                #pragma unroll
                for (int r = 0; r < 8; ++r) s[r] += rowbuf[r][k] * w;
            }
            #pragma unroll
            for (int r = 0; r < 8; ++r)
                if (s[r] > best[r]) { best[r] = s[r]; bidx[r] = c; }  // cc ascending: strict > keeps lower col on tie
        }
        #pragma unroll
        for (int r = 0; r < 8; ++r) {
            float b = best[r]; int i = bidx[r];
            #pragma unroll
            for (int d = 32; d > 0; d >>= 1) {
                float ob = __shfl_xor(b, d, 64);
                int oi = __shfl_xor(i, d, 64);
                if (ob > b || (ob == b && oi < i)) { b = ob; i = oi; }
            }
            if (lane == 0) { rbest[r][wid] = b; ridx[r][wid] = i; }
        }
        __syncthreads();
        if (tid < nr) {
            int r = tid;
            float b = rbest[r][0]; int i = ridx[r][0];
            #pragma unroll
            for (int w = 1; w < 4; ++w) {
                if (rbest[r][w] > b || (rbest[r][w] == b && ridx[r][w] < i)) { b = rbest[r][w]; i = ridx[r][w]; }
            }
            preds[susp_rows[base + r]] = (float)i;
        }
    }
}

// ---------------- launcher ----------------

extern "C" void kernel_launch(void* const* d_in, const int* in_sizes, int n_in,
                              void* d_out, int out_size, void* d_ws, size_t ws_size,
                              hipStream_t stream) {
    const float* x  = (const float*)d_in[0];
    const int*   e1 = (const int*)d_in[1];
    const int*   e2 = (const int*)d_in[2];
    const float* W1 = (const float*)d_in[3];
    const float* b1 = (const float*)d_in[4];
    const float* W2 = (const float*)d_in[5];
    const float* b2 = (const float*)d_in[6];

    float* out     = (float*)d_out;
    float* logits1 = out;
    float* logits2 = out + (size_t)N_NODES * CH;
    float* preds   = out + 2 * (size_t)N_NODES * CH;

    const size_t NEED = 109600016;
    if (ws_size < NEED) return;

    char* ws = (char*)d_ws;
    float* A      = (float*)(ws);                 // 102.4 MB fp32 scratch
    int*   cnt    = (int*)(ws + 102400000);
    int*   offs   = (int*)(ws + 102600000);
    int*   cursor = (int*)(ws + 102800016);
    float* dinv   = (float*)(ws + 103000016);
    int*   srcs   = (int*)(ws + 103200016);
    float* enorm  = (float*)(ws + 106400016);

    // conv2 bf16 scratch carved from regions free during conv2:
    unsigned short* xb  = (unsigned short*)logits1;                    // 51.2 MB in logits1 region
    unsigned short* Wtb = (unsigned short*)((char*)logits1 + 51200000);// 0.5 MB, also logits1 region
    unsigned short* h1b = (unsigned short*)A;                          // 51.2 MB
    unsigned short* h2b = (unsigned short*)((char*)A + 51200000);      // 51.2 MB

    // conv1 bf16x3 scratch, live only after conv1 propagation (srcs/enorm dead then):
    unsigned short* Wt1h = (unsigned short*)srcs;    // 0.5 MB in srcs region (3.2 MB)
    unsigned short* Wt1l = (unsigned short*)enorm;   // 0.5 MB in enorm region (3.2 MB)
    int* susp_cnt  = (int*)cursor;                   // cursor region dead after fill_csr
    int* susp_rows = (int*)cursor + 1;

    // ================= conv2 (bf16 path) first =================
    {
        hipMemsetAsync(cnt, 0, N_NODES * sizeof(int), stream);
        hipMemsetAsync(cursor, 0, N_NODES * sizeof(int), stream);
        count_col<<<(N_EDGES + 255) / 256, 256, 0, stream>>>(e2 + N_EDGES, cnt);
        make_dinv<<<(N_NODES + 255) / 256, 256, 0, stream>>>(cnt, dinv);
        scan_offsets<<<1, 1024, 0, stream>>>(cnt, offs);
        fill_csr<<<(N_EDGES + 255) / 256, 256, 0, stream>>>(e2, offs, cursor, dinv, srcs, enorm);

        convert_x_bf16<<<(N_NODES * CH / 8 + 255) / 256, 256, 0, stream>>>(x, xb);
        convert_w_t<<<(512 * 512) / 256, 256, 0, stream>>>(W2, Wtb);

        propagate_bf16<<<N_NODES / 2, 128, 0, stream>>>(xb, h1b, offs, srcs, enorm, dinv);
        propagate_bf16<<<N_NODES / 2, 128, 0, stream>>>(h1b, h2b, offs, srcs, enorm, dinv);

        dim3 g((N_NODES + BM2 - 1) / BM2, CH / BN2);
        gemm_bf16<<<g, 256, 0, stream>>>(h2b, Wtb, b2, logits2);
        softmax_rows<<<N_NODES / 4, 256, 0, stream>>>(logits2, logits2, nullptr, nullptr, nullptr);
    }

    // ================= conv1 (fp32 propagation + bf16x3 MFMA GEMM, argmax-exact via fixup) =================
    {
        hipMemsetAsync(cnt, 0, N_NODES * sizeof(int), stream);
        hipMemsetAsync(cursor, 0, N_NODES * sizeof(int), stream);
        count_col<<<(N_EDGES + 255) / 256, 256, 0, stream>>>(e1 + N_EDGES, cnt);
        make_dinv<<<(N_NODES + 255) / 256, 256, 0, stream>>>(cnt, dinv);
        scan_offsets<<<1, 1024, 0, stream>>>(cnt, offs);
        fill_csr<<<(N_EDGES + 255) / 256, 256, 0, stream>>>(e1, offs, cursor, dinv, srcs, enorm);

        propagate<<<N_NODES, 128, 0, stream>>>(x, logits1, offs, srcs, enorm, dinv);
        propagate<<<N_NODES, 128, 0, stream>>>(logits1, A, offs, srcs, enorm, dinv);

        // srcs/enorm now dead -> reuse for split W1; cursor dead -> suspect list
        convert_w_t_split<<<(512 * 512) / 256, 256, 0, stream>>>(W1, Wt1h, Wt1l);
        hipMemsetAsync(susp_cnt, 0, sizeof(int), stream);

        dim3 g((N_NODES + BM3 - 1) / BM3, CH / BN3);
        gemm_bf16x3<<<g, 256, 0, stream>>>(A, Wt1h, Wt1l, b1, logits1);
        softmax_rows<<<N_NODES / 4, 256, 0, stream>>>(logits1, logits1, preds, susp_cnt, susp_rows);
        fix_preds<<<128, 256, 0, stream>>>(A, W1, b1, susp_cnt, susp_rows, preds);
    }
}

// Round 3
// 1749.433 us; speedup vs baseline: 1.8496x; 1.8496x over previous
//
#include <hip/hip_runtime.h>
#include <hip/hip_bf16.h>
#include <cstdint>
#include <cstddef>

#define N_NODES 50000
#define N_EDGES 800000
#define CH 512

typedef __attribute__((ext_vector_type(8))) short bf16x8;
typedef __attribute__((ext_vector_type(4))) float f32x4;

__device__ inline unsigned short f2b(float f) {
    __hip_bfloat16 h = __float2bfloat16(f);
    return *(unsigned short*)&h;
}
__device__ inline float blo(unsigned int u) {  // low 16 bits as bf16 -> f32
    union { unsigned int i; float f; } v; v.i = u << 16; return v.f;
}
__device__ inline float bhi(unsigned int u) {  // high 16 bits as bf16 -> f32
    union { unsigned int i; float f; } v; v.i = u & 0xffff0000u; return v.f;
}
__device__ inline unsigned int pack2(unsigned short a, unsigned short b) {
    return (unsigned)a | ((unsigned)b << 16);
}

// ---------------- CSR build ----------------

__global__ __launch_bounds__(256) void count_col(const int* __restrict__ col, int* __restrict__ cnt) {
    int e = blockIdx.x * 256 + threadIdx.x;
    if (e < N_EDGES) atomicAdd(&cnt[col[e]], 1);
}

__global__ __launch_bounds__(256) void make_dinv(const int* __restrict__ cnt, float* __restrict__ dinv) {
    int i = blockIdx.x * 256 + threadIdx.x;
    if (i < N_NODES) dinv[i] = rsqrtf((float)(cnt[i] + 1));  // +1 self loop
}

__global__ __launch_bounds__(1024) void scan_offsets(const int* __restrict__ cnt, int* __restrict__ offs) {
    __shared__ int wsum[16];
    __shared__ int s_carry;
    int tid = threadIdx.x;
    int lane = tid & 63, wid = tid >> 6;
    if (tid == 0) s_carry = 0;
    __syncthreads();
    const int n = N_NODES;
    for (int c0 = 0; c0 < n; c0 += 1024) {
        int i = c0 + tid;
        int v = (i < n) ? cnt[i] : 0;
        int incl = v;
        #pragma unroll
        for (int d = 1; d < 64; d <<= 1) {
            int t = __shfl_up(incl, d, 64);
            if (lane >= d) incl += t;
        }
        if (lane == 63) wsum[wid] = incl;
        __syncthreads();
        int wbase = 0;
        for (int w = 0; w < wid; ++w) wbase += wsum[w];
        int excl = s_carry + wbase + incl - v;
        if (i < n) offs[i] = excl;
        int ctot = wbase + incl;
        __syncthreads();
        if (tid == 1023) s_carry += ctot;
        __syncthreads();
    }
    if (tid == 0) offs[n] = s_carry;
}

__global__ __launch_bounds__(256) void fill_csr(const int* __restrict__ edges,
                                                const int* __restrict__ offs,
                                                int* __restrict__ cursor,
                                                const float* __restrict__ dinv,
                                                int* __restrict__ srcs,
                                                float* __restrict__ enorm) {
    int e = blockIdx.x * 256 + threadIdx.x;
    if (e >= N_EDGES) return;
    int r = edges[e];            // source
    int c = edges[N_EDGES + e];  // destination
    int p = offs[c] + atomicAdd(&cursor[c], 1);
    srcs[p] = r;
    enorm[p] = dinv[r] * dinv[c];
}

// ---------------- converters ----------------

__global__ __launch_bounds__(256) void convert_x_bf16(const float* __restrict__ x, unsigned short* __restrict__ xb) {
    int i8 = blockIdx.x * 256 + threadIdx.x;  // 8 floats per thread
    const float4* x4 = (const float4*)x;
    float4 a = x4[2 * i8], b = x4[2 * i8 + 1];
    unsigned int o[4];
    o[0] = pack2(f2b(a.x), f2b(a.y));
    o[1] = pack2(f2b(a.z), f2b(a.w));
    o[2] = pack2(f2b(b.x), f2b(b.y));
    o[3] = pack2(f2b(b.z), f2b(b.w));
    ((uint4*)xb)[i8] = make_uint4(o[0], o[1], o[2], o[3]);
}

// Wt[n][k] = bf16(W[k][n])
__global__ __launch_bounds__(256) void convert_w_t(const float* __restrict__ W, unsigned short* __restrict__ Wt) {
    int id = blockIdx.x * 256 + threadIdx.x;
    int k = id >> 9, n = id & 511;
    Wt[(size_t)n * 512 + k] = f2b(W[(size_t)k * 512 + n]);
}

// Split W into hi/lo bf16, transposed n-major: Wth[n][k] + Wtl[n][k] ~= W[k][n] (fp32)
__global__ __launch_bounds__(256) void convert_w_t_split(const float* __restrict__ W,
                                                         unsigned short* __restrict__ Wth,
                                                         unsigned short* __restrict__ Wtl) {
    int id = blockIdx.x * 256 + threadIdx.x;
    int k = id >> 9, n = id & 511;
    float f = W[(size_t)k * 512 + n];
    unsigned short hb = f2b(f);  // RTN
    union { unsigned int u; float ff; } t; t.u = (unsigned)hb << 16;
    float lo = f - t.ff;
    Wth[(size_t)n * 512 + k] = hb;
    Wtl[(size_t)n * 512 + k] = f2b(lo);
}

// ---------------- fp32 propagation (conv1): unroll-4 gather ----------------

__global__ __launch_bounds__(128) void propagate(const float* __restrict__ h, float* __restrict__ out,
                                                 const int* __restrict__ offs,
                                                 const int* __restrict__ srcs,
                                                 const float* __restrict__ enorm,
                                                 const float* __restrict__ dinv) {
    int node = blockIdx.x;
    int t = threadIdx.x;  // 128 threads * float4 = 512 channels
    const float4* h4 = (const float4*)h;
    float di = dinv[node];
    float w0 = di * di;
    float4 v = h4[(size_t)node * 128 + t];
    float4 acc = make_float4(v.x * w0, v.y * w0, v.z * w0, v.w * w0);
    int e0 = offs[node], e1 = offs[node + 1];
    int e = e0;
    int eu = e0 + ((e1 - e0) & ~3);
    for (; e < eu; e += 4) {
        int s0 = srcs[e], s1 = srcs[e + 1], s2 = srcs[e + 2], s3 = srcs[e + 3];
        float wa = enorm[e], wb = enorm[e + 1], wc = enorm[e + 2], wd = enorm[e + 3];
        float4 u0 = h4[(size_t)s0 * 128 + t];
        float4 u1 = h4[(size_t)s1 * 128 + t];
        float4 u2 = h4[(size_t)s2 * 128 + t];
        float4 u3 = h4[(size_t)s3 * 128 + t];
        acc.x += u0.x * wa; acc.y += u0.y * wa; acc.z += u0.z * wa; acc.w += u0.w * wa;
        acc.x += u1.x * wb; acc.y += u1.y * wb; acc.z += u1.z * wb; acc.w += u1.w * wb;
        acc.x += u2.x * wc; acc.y += u2.y * wc; acc.z += u2.z * wc; acc.w += u2.w * wc;
        acc.x += u3.x * wd; acc.y += u3.y * wd; acc.z += u3.z * wd; acc.w += u3.w * wd;
    }
    for (; e < e1; ++e) {
        int s = srcs[e];
        float w = enorm[e];
        float4 u = h4[(size_t)s * 128 + t];
        acc.x += u.x * w; acc.y += u.y * w; acc.z += u.z * w; acc.w += u.w * w;
    }
    ((float4*)out)[(size_t)node * 128 + t] = acc;
}

// ---------------- bf16 propagation (conv2): wave per node, fp32 accum ----------------

__global__ __launch_bounds__(128) void propagate_bf16(const unsigned short* __restrict__ hb,
                                                      unsigned short* __restrict__ outb,
                                                      const int* __restrict__ offs,
                                                      const int* __restrict__ srcs,
                                                      const float* __restrict__ enorm,
                                                      const float* __restrict__ dinv) {
    int node = blockIdx.x * 2 + (threadIdx.x >> 6);
    int lane = threadIdx.x & 63;  // lane handles 8 channels (16 B)
    const uint4* h16 = (const uint4*)hb;  // 64 uint4 per row
    float di = dinv[node];
    float w0 = di * di;
    float acc[8];
    uint4 sv = h16[(size_t)node * 64 + lane];
    acc[0] = blo(sv.x) * w0; acc[1] = bhi(sv.x) * w0;
    acc[2] = blo(sv.y) * w0; acc[3] = bhi(sv.y) * w0;
    acc[4] = blo(sv.z) * w0; acc[5] = bhi(sv.z) * w0;
    acc[6] = blo(sv.w) * w0; acc[7] = bhi(sv.w) * w0;
    int e0 = offs[node], e1 = offs[node + 1];
    int e = e0;
    int eu = e0 + ((e1 - e0) & ~3);
    for (; e < eu; e += 4) {
        int s0 = srcs[e], s1 = srcs[e + 1], s2 = srcs[e + 2], s3 = srcs[e + 3];
        float wa = enorm[e], wb = enorm[e + 1], wc = enorm[e + 2], wd = enorm[e + 3];
        uint4 u0 = h16[(size_t)s0 * 64 + lane];
        uint4 u1 = h16[(size_t)s1 * 64 + lane];
        uint4 u2 = h16[(size_t)s2 * 64 + lane];
        uint4 u3 = h16[(size_t)s3 * 64 + lane];
        acc[0] += blo(u0.x) * wa; acc[1] += bhi(u0.x) * wa;
        acc[2] += blo(u0.y) * wa; acc[3] += bhi(u0.y) * wa;
        acc[4] += blo(u0.z) * wa; acc[5] += bhi(u0.z) * wa;
        acc[6] += blo(u0.w) * wa; acc[7] += bhi(u0.w) * wa;
        acc[0] += blo(u1.x) * wb; acc[1] += bhi(u1.x) * wb;
        acc[2] += blo(u1.y) * wb; acc[3] += bhi(u1.y) * wb;
        acc[4] += blo(u1.z) * wb; acc[5] += bhi(u1.z) * wb;
        acc[6] += blo(u1.w) * wb; acc[7] += bhi(u1.w) * wb;
        acc[0] += blo(u2.x) * wc; acc[1] += bhi(u2.x) * wc;
        acc[2] += blo(u2.y) * wc; acc[3] += bhi(u2.y) * wc;
        acc[4] += blo(u2.z) * wc; acc[5] += bhi(u2.z) * wc;
        acc[6] += blo(u2.w) * wc; acc[7] += bhi(u2.w) * wc;
        acc[0] += blo(u3.x) * wd; acc[1] += bhi(u3.x) * wd;
        acc[2] += blo(u3.y) * wd; acc[3] += bhi(u3.y) * wd;
        acc[4] += blo(u3.z) * wd; acc[5] += bhi(u3.z) * wd;
        acc[6] += blo(u3.w) * wd; acc[7] += bhi(u3.w) * wd;
    }
    for (; e < e1; ++e) {
        int s = srcs[e];
        float w = enorm[e];
        uint4 u = h16[(size_t)s * 64 + lane];
        acc[0] += blo(u.x) * w; acc[1] += bhi(u.x) * w;
        acc[2] += blo(u.y) * w; acc[3] += bhi(u.y) * w;
        acc[4] += blo(u.z) * w; acc[5] += bhi(u.z) * w;
        acc[6] += blo(u.w) * w; acc[7] += bhi(u.w) * w;
    }
    unsigned int o0 = pack2(f2b(acc[0]), f2b(acc[1]));
    unsigned int o1 = pack2(f2b(acc[2]), f2b(acc[3]));
    unsigned int o2 = pack2(f2b(acc[4]), f2b(acc[5]));
    unsigned int o3 = pack2(f2b(acc[6]), f2b(acc[7]));
    ((uint4*)outb)[(size_t)node * 64 + lane] = make_uint4(o0, o1, o2, o3);
}

// ---------------- bf16 MFMA GEMM (conv2): C[M,512] = Ab @ Wt^T + bias ----------------
// Block: 256 thr = 4 waves (2x2), tile BM2=128 x BN2=64, BK2=32.

#define BM2 128
#define BN2 64
#define BK2 32
#define LDP 40  // LDS row pitch in shorts (80 B -> 2-way bank aliasing only)

__global__ __launch_bounds__(256) void gemm_bf16(const unsigned short* __restrict__ Ab,
                                                 const unsigned short* __restrict__ Wt,
                                                 const float* __restrict__ bias,
                                                 float* __restrict__ C) {
    __shared__ short Alds[BM2 * LDP];
    __shared__ short Blds[BN2 * LDP];
    int tid = threadIdx.x;
    int lane = tid & 63;
    int wid = tid >> 6;
    int wm = wid & 1;   // 0/1 -> 64-row half
    int wn = wid >> 1;  // 0/1 -> 32-col half
    int bm = blockIdx.x * BM2;
    int bn = blockIdx.y * BN2;

    f32x4 acc[4][2] = {};

    int arow0 = tid >> 2, aq = tid & 3;
    int brow = tid >> 2, bq = tid & 3;

    for (int k0 = 0; k0 < CH; k0 += BK2) {
        #pragma unroll
        for (int h = 0; h < 2; ++h) {
            int row = arow0 + h * 64;
            int gr = bm + row;
            uint4 v = make_uint4(0u, 0u, 0u, 0u);
            if (gr < N_NODES) v = *(const uint4*)&Ab[(size_t)gr * CH + k0 + aq * 8];
            *(uint4*)&Alds[row * LDP + aq * 8] = v;
        }
        {
            uint4 v = *(const uint4*)&Wt[(size_t)(bn + brow) * CH + k0 + bq * 8];
            *(uint4*)&Blds[brow * LDP + bq * 8] = v;
        }
        __syncthreads();

        bf16x8 af[4], bf[2];
        #pragma unroll
        for (int mt = 0; mt < 4; ++mt)
            af[mt] = *(const bf16x8*)&Alds[(wm * 64 + mt * 16 + (lane & 15)) * LDP + (lane >> 4) * 8];
        #pragma unroll
        for (int nt = 0; nt < 2; ++nt)
            bf[nt] = *(const bf16x8*)&Blds[(wn * 32 + nt * 16 + (lane & 15)) * LDP + (lane >> 4) * 8];
        #pragma unroll
        for (int mt = 0; mt < 4; ++mt)
            #pragma unroll
            for (int nt = 0; nt < 2; ++nt)
                acc[mt][nt] = __builtin_amdgcn_mfma_f32_16x16x32_bf16(af[mt], bf[nt], acc[mt][nt], 0, 0, 0);
        __syncthreads();
    }

    #pragma unroll
    for (int mt = 0; mt < 4; ++mt) {
        #pragma unroll
        for (int nt = 0; nt < 2; ++nt) {
            int col = bn + wn * 32 + nt * 16 + (lane & 15);
            float bv = bias[col];
            #pragma unroll
            for (int r = 0; r < 4; ++r) {
                int row = bm + wm * 64 + mt * 16 + (lane >> 4) * 4 + r;
                if (row < N_NODES) C[(size_t)row * CH + col] = acc[mt][nt][r] + bv;
            }
        }
    }
}

// ---------------- bf16x3 split MFMA GEMM (conv1): C = A(f32) @ W + bias ----------------
// A stays fp32 in memory; hi/lo bf16 split happens during LDS staging.
// C ~= A_hi@W_hi + A_lo@W_hi + A_hi@W_lo   (error bound ~3*2^-18*||a||*||w|| ~ 1.5e-5)

#define BM3 128
#define BN3 64
#define BK3 32
#define LDP3 40

__global__ __launch_bounds__(256) void gemm_bf16x3(const float* __restrict__ A,
                                                   const unsigned short* __restrict__ Wth,
                                                   const unsigned short* __restrict__ Wtl,
                                                   const float* __restrict__ bias,
                                                   float* __restrict__ C) {
    __shared__ short Ah[BM3 * LDP3];
    __shared__ short Al[BM3 * LDP3];
    __shared__ short Bh[BN3 * LDP3];
    __shared__ short Bl[BN3 * LDP3];
    int tid = threadIdx.x;
    int lane = tid & 63;
    int wid = tid >> 6;
    int wm = wid & 1;
    int wn = wid >> 1;
    int bm = blockIdx.x * BM3;
    int bn = blockIdx.y * BN3;

    f32x4 acc[4][2] = {};

    int arow = tid >> 1, aseg = tid & 1;
    int ga = bm + arow;
    bool aval = ga < N_NODES;
    const float4* A4 = (const float4*)A;
    int brow = tid >> 2, bq = tid & 3;

    for (int k0 = 0; k0 < CH; k0 += BK3) {
        {
            size_t base = (size_t)ga * 128 + (k0 >> 2) + aseg * 4;
            unsigned short h[16], l[16];
            #pragma unroll
            for (int v = 0; v < 4; ++v) {
                float4 f = aval ? A4[base + v] : make_float4(0.f, 0.f, 0.f, 0.f);
                float fs[4] = {f.x, f.y, f.z, f.w};
                #pragma unroll
                for (int j = 0; j < 4; ++j) {
                    unsigned short hb = f2b(fs[j]);       // RTN hi
                    union { unsigned int u; float ff; } t; t.u = (unsigned)hb << 16;
                    float lo = fs[j] - t.ff;              // exact remainder
                    h[v * 4 + j] = hb;
                    l[v * 4 + j] = f2b(lo);
                }
            }
            uint4 H0 = make_uint4(pack2(h[0], h[1]), pack2(h[2], h[3]), pack2(h[4], h[5]), pack2(h[6], h[7]));
            uint4 H1 = make_uint4(pack2(h[8], h[9]), pack2(h[10], h[11]), pack2(h[12], h[13]), pack2(h[14], h[15]));
            uint4 L0 = make_uint4(pack2(l[0], l[1]), pack2(l[2], l[3]), pack2(l[4], l[5]), pack2(l[6], l[7]));
            uint4 L1 = make_uint4(pack2(l[8], l[9]), pack2(l[10], l[11]), pack2(l[12], l[13]), pack2(l[14], l[15]));
            *(uint4*)&Ah[arow * LDP3 + aseg * 16] = H0;
            *(uint4*)&Ah[arow * LDP3 + aseg * 16 + 8] = H1;
            *(uint4*)&Al[arow * LDP3 + aseg * 16] = L0;
            *(uint4*)&Al[arow * LDP3 + aseg * 16 + 8] = L1;
        }
        *(uint4*)&Bh[brow * LDP3 + bq * 8] = *(const uint4*)&Wth[(size_t)(bn + brow) * CH + k0 + bq * 8];
        *(uint4*)&Bl[brow * LDP3 + bq * 8] = *(const uint4*)&Wtl[(size_t)(bn + brow) * CH + k0 + bq * 8];
        __syncthreads();

        bf16x8 afh[4], afl[4], bfh[2], bfl[2];
        #pragma unroll
        for (int mt = 0; mt < 4; ++mt) {
            int off = (wm * 64 + mt * 16 + (lane & 15)) * LDP3 + (lane >> 4) * 8;
            afh[mt] = *(const bf16x8*)&Ah[off];
            afl[mt] = *(const bf16x8*)&Al[off];
        }
        #pragma unroll
        for (int nt = 0; nt < 2; ++nt) {
            int off = (wn * 32 + nt * 16 + (lane & 15)) * LDP3 + (lane >> 4) * 8;
            bfh[nt] = *(const bf16x8*)&Bh[off];
            bfl[nt] = *(const bf16x8*)&Bl[off];
        }
        #pragma unroll
        for (int mt = 0; mt < 4; ++mt)
            #pragma unroll
            for (int nt = 0; nt < 2; ++nt) {
                acc[mt][nt] = __builtin_amdgcn_mfma_f32_16x16x32_bf16(afh[mt], bfh[nt], acc[mt][nt], 0, 0, 0);
                acc[mt][nt] = __builtin_amdgcn_mfma_f32_16x16x32_bf16(afl[mt], bfh[nt], acc[mt][nt], 0, 0, 0);
                acc[mt][nt] = __builtin_amdgcn_mfma_f32_16x16x32_bf16(afh[mt], bfl[nt], acc[mt][nt], 0, 0, 0);
            }
        __syncthreads();
    }

    #pragma unroll
    for (int mt = 0; mt < 4; ++mt) {
        #pragma unroll
        for (int nt = 0; nt < 2; ++nt) {
            int col = bn + wn * 32 + nt * 16 + (lane & 15);
            float bv = bias[col];
            #pragma unroll
            for (int r = 0; r < 4; ++r) {
                int row = bm + wm * 64 + mt * 16 + (lane >> 4) * 4 + r;
                if (row < N_NODES) C[(size_t)row * CH + col] = acc[mt][nt][r] + bv;
            }
        }
    }
}

// ---------------- Softmax (+argmax + top-2 gap suspects), one wave per row ----------------
// bf16x3 logit error bound ~1.5e-5; flag gap < 2e-4 (6x margin).
// Expected suspects ~ 50000 * (2e-4 / 0.018) ~ 550 rows.

#define GAP_THR 2.0e-4f
#define SUSP_CAP 49999  // susp_rows lives in the 50000-int cursor region (1 int for count)

__global__ __launch_bounds__(256) void softmax_rows(const float* __restrict__ X, float* __restrict__ P,
                                                    float* __restrict__ preds,
                                                    int* __restrict__ susp_cnt,
                                                    int* __restrict__ susp_rows) {
    int row = blockIdx.x * 4 + (threadIdx.x >> 6);
    int lane = threadIdx.x & 63;
    if (row >= N_NODES) return;
    const float4* x4 = (const float4*)(X + (size_t)row * CH);
    float4 v0 = x4[lane];
    float4 v1 = x4[lane + 64];
    float vals[8] = {v0.x, v0.y, v0.z, v0.w, v1.x, v1.y, v1.z, v1.w};
    float m = vals[0];
    float m2 = -INFINITY;
    int mi = lane * 4;
    #pragma unroll
    for (int j = 1; j < 8; ++j) {
        int c = (j < 4) ? (lane * 4 + j) : (256 + lane * 4 + (j - 4));
        if (vals[j] > m) { m2 = m; m = vals[j]; mi = c; }
        else if (vals[j] > m2) { m2 = vals[j]; }
    }
    #pragma unroll
    for (int d = 32; d > 0; d >>= 1) {
        float om = __shfl_xor(m, d, 64);
        int oi = __shfl_xor(mi, d, 64);
        float om2 = __shfl_xor(m2, d, 64);
        if (om > m || (om == m && oi < mi)) {
            m2 = fmaxf(m, om2);
            m = om; mi = oi;
        } else {
            m2 = fmaxf(m2, om);
        }
    }
    float s = 0.f;
    float ex[8];
    #pragma unroll
    for (int j = 0; j < 8; ++j) { ex[j] = __expf(vals[j] - m); s += ex[j]; }
    #pragma unroll
    for (int d = 32; d > 0; d >>= 1) s += __shfl_xor(s, d, 64);
    float inv = 1.0f / s;
    float4 o0 = make_float4(ex[0] * inv, ex[1] * inv, ex[2] * inv, ex[3] * inv);
    float4 o1 = make_float4(ex[4] * inv, ex[5] * inv, ex[6] * inv, ex[7] * inv);
    float4* p4 = (float4*)(P + (size_t)row * CH);
    p4[lane] = o0;
    p4[lane + 64] = o1;
    if (preds != nullptr && lane == 0) {
        preds[row] = (float)mi;
        if (m - m2 < GAP_THR) {
            int p = atomicAdd(susp_cnt, 1);
            if (p < SUSP_CAP) susp_rows[p] = row;
        }
    }
}

// ---------------- exact fp32 argmax fixup for suspect rows ----------------
// For each suspect row: recompute logits = A_row(f32) @ W + bias in fp32, rewrite preds.

__global__ __launch_bounds__(256) void fix_preds(const float* __restrict__ A, const float* __restrict__ W,
                                                 const float* __restrict__ bias,
                                                 const int* __restrict__ susp_cnt,
                                                 const int* __restrict__ susp_rows,
                                                 float* __restrict__ preds) {
    __shared__ float rowbuf[8][512];
    __shared__ float rbest[8][4];
    __shared__ int ridx[8][4];
    int cnt = *susp_cnt;
    if (cnt > SUSP_CAP) cnt = SUSP_CAP;
    int tid = threadIdx.x, lane = tid & 63, wid = tid >> 6;
    for (int base = blockIdx.x * 8; base < cnt; base += gridDim.x * 8) {
        int nr = min(8, cnt - base);
        __syncthreads();  // protect rowbuf reuse across sweep iterations
        for (int r = 0; r < nr; ++r) {
            int row = susp_rows[base + r];
            if (tid < 128) ((float4*)rowbuf[r])[tid] = ((const float4*)&A[(size_t)row * 512])[tid];
        }
        __syncthreads();
        float best[8]; int bidx[8];
        #pragma unroll
        for (int r = 0; r < 8; ++r) { best[r] = -INFINITY; bidx[r] = 0; }
        for (int cc = 0; cc < 2; ++cc) {
            int c = cc * 256 + tid;
            float bv = bias[c];
            float s[8];
            #pragma unroll
            for (int r = 0; r < 8; ++r) s[r] = bv;
            #pragma unroll 8
            for (int k = 0; k < 512; ++k) {
                float w = W[(size_t)k * 512 + c];
                #pragma unroll
                for (int r = 0; r < 8; ++r) s[r] += rowbuf[r][k] * w;
            }
            #pragma unroll
            for (int r = 0; r < 8; ++r)
                if (s[r] > best[r]) { best[r] = s[r]; bidx[r] = c; }  // cc ascending: strict > keeps lower col on tie
        }
        #pragma unroll
        for (int r = 0; r < 8; ++r) {
            float b = best[r]; int i = bidx[r];
            #pragma unroll
            for (int d = 32; d > 0; d >>= 1) {
                float ob = __shfl_xor(b, d, 64);
                int oi = __shfl_xor(i, d, 64);
                if (ob > b || (ob == b && oi < i)) { b = ob; i = oi; }
            }
            if (lane == 0) { rbest[r][wid] = b; ridx[r][wid] = i; }
        }
        __syncthreads();
        if (tid < nr) {
            int r = tid;
            float b = rbest[r][0]; int i = ridx[r][0];
            #pragma unroll
            for (int w = 1; w < 4; ++w) {
                if (rbest[r][w] > b || (rbest[r][w] == b && ridx[r][w] < i)) { b = rbest[r][w]; i = ridx[r][w]; }
            }
            preds[susp_rows[base + r]] = (float)i;
        }
    }
}

// ---------------- launcher ----------------

extern "C" void kernel_launch(void* const* d_in, const int* in_sizes, int n_in,
                              void* d_out, int out_size, void* d_ws, size_t ws_size,
                              hipStream_t stream) {
    const float* x  = (const float*)d_in[0];
    const int*   e1 = (const int*)d_in[1];
    const int*   e2 = (const int*)d_in[2];
    const float* W1 = (const float*)d_in[3];
    const float* b1 = (const float*)d_in[4];
    const float* W2 = (const float*)d_in[5];
    const float* b2 = (const float*)d_in[6];

    float* out     = (float*)d_out;
    float* logits1 = out;
    float* logits2 = out + (size_t)N_NODES * CH;
    float* preds   = out + 2 * (size_t)N_NODES * CH;

    const size_t NEED = 109600016;
    if (ws_size < NEED) return;

    char* ws = (char*)d_ws;
    float* A      = (float*)(ws);                 // 102.4 MB fp32 scratch
    int*   cnt    = (int*)(ws + 102400000);
    int*   offs   = (int*)(ws + 102600000);
    int*   cursor = (int*)(ws + 102800016);
    float* dinv   = (float*)(ws + 103000016);
    int*   srcs   = (int*)(ws + 103200016);
    float* enorm  = (float*)(ws + 106400016);

    // conv2 bf16 scratch carved from regions free during conv2:
    unsigned short* xb  = (unsigned short*)logits1;                    // 51.2 MB in logits1 region
    unsigned short* Wtb = (unsigned short*)((char*)logits1 + 51200000);// 0.5 MB, also logits1 region
    unsigned short* h1b = (unsigned short*)A;                          // 51.2 MB
    unsigned short* h2b = (unsigned short*)((char*)A + 51200000);      // 51.2 MB

    // conv1 bf16x3 scratch, live only after conv1 propagation (srcs/enorm dead then):
    unsigned short* Wt1h = (unsigned short*)srcs;    // 0.5 MB in srcs region (3.2 MB)
    unsigned short* Wt1l = (unsigned short*)enorm;   // 0.5 MB in enorm region (3.2 MB)
    int* susp_cnt  = (int*)cursor;                   // cursor region dead after fill_csr
    int* susp_rows = (int*)cursor + 1;

    // ================= conv2 (bf16 path) first =================
    {
        hipMemsetAsync(cnt, 0, N_NODES * sizeof(int), stream);
        hipMemsetAsync(cursor, 0, N_NODES * sizeof(int), stream);
        count_col<<<(N_EDGES + 255) / 256, 256, 0, stream>>>(e2 + N_EDGES, cnt);
        make_dinv<<<(N_NODES + 255) / 256, 256, 0, stream>>>(cnt, dinv);
        scan_offsets<<<1, 1024, 0, stream>>>(cnt, offs);
        fill_csr<<<(N_EDGES + 255) / 256, 256, 0, stream>>>(e2, offs, cursor, dinv, srcs, enorm);

        convert_x_bf16<<<(N_NODES * CH / 8 + 255) / 256, 256, 0, stream>>>(x, xb);
        convert_w_t<<<(512 * 512) / 256, 256, 0, stream>>>(W2, Wtb);

        propagate_bf16<<<N_NODES / 2, 128, 0, stream>>>(xb, h1b, offs, srcs, enorm, dinv);
        propagate_bf16<<<N_NODES / 2, 128, 0, stream>>>(h1b, h2b, offs, srcs, enorm, dinv);

        dim3 g((N_NODES + BM2 - 1) / BM2, CH / BN2);
        gemm_bf16<<<g, 256, 0, stream>>>(h2b, Wtb, b2, logits2);
        softmax_rows<<<N_NODES / 4, 256, 0, stream>>>(logits2, logits2, nullptr, nullptr, nullptr);
    }

    // ================= conv1 (fp32 propagation + bf16x3 MFMA GEMM, argmax-exact via fixup) =================
    {
        hipMemsetAsync(cnt, 0, N_NODES * sizeof(int), stream);
        hipMemsetAsync(cursor, 0, N_NODES * sizeof(int), stream);
        count_col<<<(N_EDGES + 255) / 256, 256, 0, stream>>>(e1 + N_EDGES, cnt);
        make_dinv<<<(N_NODES + 255) / 256, 256, 0, stream>>>(cnt, dinv);
        scan_offsets<<<1, 1024, 0, stream>>>(cnt, offs);
        fill_csr<<<(N_EDGES + 255) / 256, 256, 0, stream>>>(e1, offs, cursor, dinv, srcs, enorm);

        propagate<<<N_NODES, 128, 0, stream>>>(x, logits1, offs, srcs, enorm, dinv);
        propagate<<<N_NODES, 128, 0, stream>>>(logits1, A, offs, srcs, enorm, dinv);

        // srcs/enorm now dead -> reuse for split W1; cursor dead -> suspect list
        convert_w_t_split<<<(512 * 512) / 256, 256, 0, stream>>>(W1, Wt1h, Wt1l);
        hipMemsetAsync(susp_cnt, 0, sizeof(int), stream);

        dim3 g((N_NODES + BM3 - 1) / BM3, CH / BN3);
        gemm_bf16x3<<<g, 256, 0, stream>>>(A, Wt1h, Wt1l, b1, logits1);
        softmax_rows<<<N_NODES / 4, 256, 0, stream>>>(logits1, logits1, preds, susp_cnt, susp_rows);
        fix_preds<<<400, 256, 0, stream>>>(A, W1, b1, susp_cnt, susp_rows, preds);
    }
}

// Round 4
// 1676.277 us; speedup vs baseline: 1.9304x; 1.0436x over previous
//
#include <hip/hip_runtime.h>
#include <hip/hip_bf16.h>
#include <cstdint>
#include <cstddef>

#define N_NODES 50000
#define N_EDGES 800000
#define CH 512

typedef __attribute__((ext_vector_type(8))) short bf16x8;
typedef __attribute__((ext_vector_type(4))) float f32x4;

__device__ inline unsigned short f2b(float f) {
    __hip_bfloat16 h = __float2bfloat16(f);
    return *(unsigned short*)&h;
}
__device__ inline float blo(unsigned int u) {  // low 16 bits as bf16 -> f32
    union { unsigned int i; float f; } v; v.i = u << 16; return v.f;
}
__device__ inline float bhi(unsigned int u) {  // high 16 bits as bf16 -> f32
    union { unsigned int i; float f; } v; v.i = u & 0xffff0000u; return v.f;
}
__device__ inline unsigned int pack2(unsigned short a, unsigned short b) {
    return (unsigned)a | ((unsigned)b << 16);
}

// ---------------- CSR build ----------------

__global__ __launch_bounds__(256) void count_col(const int* __restrict__ col, int* __restrict__ cnt) {
    int e = blockIdx.x * 256 + threadIdx.x;
    if (e < N_EDGES) atomicAdd(&cnt[col[e]], 1);
}

// scan_offsets also emits dinv[i] = rsqrt(cnt[i]+1)  (folds old make_dinv kernel)
__global__ __launch_bounds__(1024) void scan_offsets(const int* __restrict__ cnt, int* __restrict__ offs,
                                                     float* __restrict__ dinv) {
    __shared__ int wsum[16];
    __shared__ int s_carry;
    int tid = threadIdx.x;
    int lane = tid & 63, wid = tid >> 6;
    if (tid == 0) s_carry = 0;
    __syncthreads();
    const int n = N_NODES;
    for (int c0 = 0; c0 < n; c0 += 1024) {
        int i = c0 + tid;
        int v = (i < n) ? cnt[i] : 0;
        if (i < n) dinv[i] = rsqrtf((float)(v + 1));  // +1 self loop
        int incl = v;
        #pragma unroll
        for (int d = 1; d < 64; d <<= 1) {
            int t = __shfl_up(incl, d, 64);
            if (lane >= d) incl += t;
        }
        if (lane == 63) wsum[wid] = incl;
        __syncthreads();
        int wbase = 0;
        for (int w = 0; w < wid; ++w) wbase += wsum[w];
        int excl = s_carry + wbase + incl - v;
        if (i < n) offs[i] = excl;
        int ctot = wbase + incl;
        __syncthreads();
        if (tid == 1023) s_carry += ctot;
        __syncthreads();
    }
    if (tid == 0) offs[n] = s_carry;
}

__global__ __launch_bounds__(256) void fill_csr(const int* __restrict__ edges,
                                                const int* __restrict__ offs,
                                                int* __restrict__ cursor,
                                                const float* __restrict__ dinv,
                                                int* __restrict__ srcs,
                                                float* __restrict__ enorm) {
    int e = blockIdx.x * 256 + threadIdx.x;
    if (e >= N_EDGES) return;
    int r = edges[e];            // source
    int c = edges[N_EDGES + e];  // destination
    int p = offs[c] + atomicAdd(&cursor[c], 1);
    srcs[p] = r;
    enorm[p] = dinv[r] * dinv[c];
}

// ---------------- converters ----------------

__global__ __launch_bounds__(256) void convert_x_bf16(const float* __restrict__ x, unsigned short* __restrict__ xb) {
    int i8 = blockIdx.x * 256 + threadIdx.x;  // 8 floats per thread
    const float4* x4 = (const float4*)x;
    float4 a = x4[2 * i8], b = x4[2 * i8 + 1];
    unsigned int o[4];
    o[0] = pack2(f2b(a.x), f2b(a.y));
    o[1] = pack2(f2b(a.z), f2b(a.w));
    o[2] = pack2(f2b(b.x), f2b(b.y));
    o[3] = pack2(f2b(b.z), f2b(b.w));
    ((uint4*)xb)[i8] = make_uint4(o[0], o[1], o[2], o[3]);
}

// Wt[n][k] = bf16(W[k][n])
__global__ __launch_bounds__(256) void convert_w_t(const float* __restrict__ W, unsigned short* __restrict__ Wt) {
    int id = blockIdx.x * 256 + threadIdx.x;
    int k = id >> 9, n = id & 511;
    Wt[(size_t)n * 512 + k] = f2b(W[(size_t)k * 512 + n]);
}

// Split W into hi/lo bf16, transposed n-major: Wth[n][k] + Wtl[n][k] ~= W[k][n] (fp32)
__global__ __launch_bounds__(256) void convert_w_t_split(const float* __restrict__ W,
                                                         unsigned short* __restrict__ Wth,
                                                         unsigned short* __restrict__ Wtl) {
    int id = blockIdx.x * 256 + threadIdx.x;
    int k = id >> 9, n = id & 511;
    float f = W[(size_t)k * 512 + n];
    unsigned short hb = f2b(f);  // RTN
    union { unsigned int u; float ff; } t; t.u = (unsigned)hb << 16;
    float lo = f - t.ff;
    Wth[(size_t)n * 512 + k] = hb;
    Wtl[(size_t)n * 512 + k] = f2b(lo);
}

// ---------------- fp32 propagation (conv1): unroll-8 gather ----------------

__global__ __launch_bounds__(128) void propagate(const float* __restrict__ h, float* __restrict__ out,
                                                 const int* __restrict__ offs,
                                                 const int* __restrict__ srcs,
                                                 const float* __restrict__ enorm,
                                                 const float* __restrict__ dinv) {
    int node = blockIdx.x;
    int t = threadIdx.x;  // 128 threads * float4 = 512 channels
    const float4* h4 = (const float4*)h;
    float di = dinv[node];
    float w0 = di * di;
    float4 v = h4[(size_t)node * 128 + t];
    float4 acc = make_float4(v.x * w0, v.y * w0, v.z * w0, v.w * w0);
    int e0 = offs[node], e1 = offs[node + 1];
    int e = e0;
    int eu = e0 + ((e1 - e0) & ~7);
    for (; e < eu; e += 8) {
        int s[8]; float w[8];
        #pragma unroll
        for (int q = 0; q < 8; ++q) { s[q] = srcs[e + q]; w[q] = enorm[e + q]; }
        float4 u[8];
        #pragma unroll
        for (int q = 0; q < 8; ++q) u[q] = h4[(size_t)s[q] * 128 + t];
        #pragma unroll
        for (int q = 0; q < 8; ++q) {
            acc.x += u[q].x * w[q]; acc.y += u[q].y * w[q];
            acc.z += u[q].z * w[q]; acc.w += u[q].w * w[q];
        }
    }
    for (; e < e1; ++e) {
        int s = srcs[e];
        float w = enorm[e];
        float4 u = h4[(size_t)s * 128 + t];
        acc.x += u.x * w; acc.y += u.y * w; acc.z += u.z * w; acc.w += u.w * w;
    }
    ((float4*)out)[(size_t)node * 128 + t] = acc;
}

// ---------------- bf16 propagation (conv2): wave per node, fp32 accum, unroll-8 ----------------

__global__ __launch_bounds__(128) void propagate_bf16(const unsigned short* __restrict__ hb,
                                                      unsigned short* __restrict__ outb,
                                                      const int* __restrict__ offs,
                                                      const int* __restrict__ srcs,
                                                      const float* __restrict__ enorm,
                                                      const float* __restrict__ dinv) {
    int node = blockIdx.x * 2 + (threadIdx.x >> 6);
    int lane = threadIdx.x & 63;  // lane handles 8 channels (16 B)
    const uint4* h16 = (const uint4*)hb;  // 64 uint4 per row
    float di = dinv[node];
    float w0 = di * di;
    float acc[8];
    uint4 sv = h16[(size_t)node * 64 + lane];
    acc[0] = blo(sv.x) * w0; acc[1] = bhi(sv.x) * w0;
    acc[2] = blo(sv.y) * w0; acc[3] = bhi(sv.y) * w0;
    acc[4] = blo(sv.z) * w0; acc[5] = bhi(sv.z) * w0;
    acc[6] = blo(sv.w) * w0; acc[7] = bhi(sv.w) * w0;
    int e0 = offs[node], e1 = offs[node + 1];
    int e = e0;
    int eu = e0 + ((e1 - e0) & ~7);
    for (; e < eu; e += 8) {
        int s[8]; float w[8];
        #pragma unroll
        for (int q = 0; q < 8; ++q) { s[q] = srcs[e + q]; w[q] = enorm[e + q]; }
        uint4 u[8];
        #pragma unroll
        for (int q = 0; q < 8; ++q) u[q] = h16[(size_t)s[q] * 64 + lane];
        #pragma unroll
        for (int q = 0; q < 8; ++q) {
            acc[0] += blo(u[q].x) * w[q]; acc[1] += bhi(u[q].x) * w[q];
            acc[2] += blo(u[q].y) * w[q]; acc[3] += bhi(u[q].y) * w[q];
            acc[4] += blo(u[q].z) * w[q]; acc[5] += bhi(u[q].z) * w[q];
            acc[6] += blo(u[q].w) * w[q]; acc[7] += bhi(u[q].w) * w[q];
        }
    }
    for (; e < e1; ++e) {
        int s = srcs[e];
        float w = enorm[e];
        uint4 u = h16[(size_t)s * 64 + lane];
        acc[0] += blo(u.x) * w; acc[1] += bhi(u.x) * w;
        acc[2] += blo(u.y) * w; acc[3] += bhi(u.y) * w;
        acc[4] += blo(u.z) * w; acc[5] += bhi(u.z) * w;
        acc[6] += blo(u.w) * w; acc[7] += bhi(u.w) * w;
    }
    unsigned int o0 = pack2(f2b(acc[0]), f2b(acc[1]));
    unsigned int o1 = pack2(f2b(acc[2]), f2b(acc[3]));
    unsigned int o2 = pack2(f2b(acc[4]), f2b(acc[5]));
    unsigned int o3 = pack2(f2b(acc[6]), f2b(acc[7]));
    ((uint4*)outb)[(size_t)node * 64 + lane] = make_uint4(o0, o1, o2, o3);
}

// ---------------- bf16 MFMA GEMM (conv2): C[M,512] = Ab @ Wt^T + bias ----------------
// Block: 512 thr = 8 waves (2 row-halves x 4 col-quarters), tile BM2=128 x BN2=256, BK2=32.
// BN2=256 -> grid.y=2 -> A re-read 2x instead of 8x.

#define BM2 128
#define BN2 256
#define BK2 32
#define LDP 40  // LDS row pitch in shorts (80 B -> 2-way bank aliasing only)

__global__ __launch_bounds__(512) void gemm_bf16(const unsigned short* __restrict__ Ab,
                                                 const unsigned short* __restrict__ Wt,
                                                 const float* __restrict__ bias,
                                                 float* __restrict__ C) {
    __shared__ short Alds[BM2 * LDP];   // 10240 B
    __shared__ short Blds[BN2 * LDP];   // 20480 B
    int tid = threadIdx.x;
    int lane = tid & 63;
    int wid = tid >> 6;   // 0..7
    int wm = wid & 1;     // 64-row half
    int wn = wid >> 1;    // 0..3 -> 64-col quarter
    int bm = blockIdx.x * BM2;
    int bn = blockIdx.y * BN2;

    f32x4 acc[4][4] = {};

    int arow = tid >> 2, ak8 = (tid & 3) * 8;   // A: 4 thr/row, 8 shorts each
    int brow = tid >> 1, bk16 = (tid & 1) * 16; // B: 2 thr/row, 16 shorts each
    int ga = bm + arow;
    bool aval = ga < N_NODES;

    for (int k0 = 0; k0 < CH; k0 += BK2) {
        {
            uint4 v = make_uint4(0u, 0u, 0u, 0u);
            if (aval) v = *(const uint4*)&Ab[(size_t)ga * CH + k0 + ak8];
            *(uint4*)&Alds[arow * LDP + ak8] = v;
        }
        {
            const unsigned short* s = &Wt[(size_t)(bn + brow) * CH + k0 + bk16];
            *(uint4*)&Blds[brow * LDP + bk16] = *(const uint4*)s;
            *(uint4*)&Blds[brow * LDP + bk16 + 8] = *(const uint4*)(s + 8);
        }
        __syncthreads();

        bf16x8 af[4], bf[4];
        #pragma unroll
        for (int mt = 0; mt < 4; ++mt)
            af[mt] = *(const bf16x8*)&Alds[(wm * 64 + mt * 16 + (lane & 15)) * LDP + (lane >> 4) * 8];
        #pragma unroll
        for (int nt = 0; nt < 4; ++nt)
            bf[nt] = *(const bf16x8*)&Blds[(wn * 64 + nt * 16 + (lane & 15)) * LDP + (lane >> 4) * 8];
        #pragma unroll
        for (int mt = 0; mt < 4; ++mt)
            #pragma unroll
            for (int nt = 0; nt < 4; ++nt)
                acc[mt][nt] = __builtin_amdgcn_mfma_f32_16x16x32_bf16(af[mt], bf[nt], acc[mt][nt], 0, 0, 0);
        __syncthreads();
    }

    #pragma unroll
    for (int mt = 0; mt < 4; ++mt) {
        #pragma unroll
        for (int nt = 0; nt < 4; ++nt) {
            int col = bn + wn * 64 + nt * 16 + (lane & 15);
            float bv = bias[col];
            #pragma unroll
            for (int r = 0; r < 4; ++r) {
                int row = bm + wm * 64 + mt * 16 + (lane >> 4) * 4 + r;
                if (row < N_NODES) C[(size_t)row * CH + col] = acc[mt][nt][r] + bv;
            }
        }
    }
}

// ---------------- bf16x3 split MFMA GEMM (conv1): C = A(f32) @ W + bias ----------------
// A stays fp32 in memory; hi/lo bf16 split happens during LDS staging.
// C ~= A_hi@W_hi + A_lo@W_hi + A_hi@W_lo   (error bound ~3*2^-18*||a||*||w|| ~ 1.5e-5)
// BN3=256 -> grid.y=2 -> fp32 A re-read 2x instead of 8x.

#define BM3 128
#define BN3 256
#define BK3 32
#define LDP3 40

__global__ __launch_bounds__(512) void gemm_bf16x3(const float* __restrict__ A,
                                                   const unsigned short* __restrict__ Wth,
                                                   const unsigned short* __restrict__ Wtl,
                                                   const float* __restrict__ bias,
                                                   float* __restrict__ C) {
    __shared__ short Ah[BM3 * LDP3];   // 10240 B
    __shared__ short Al[BM3 * LDP3];   // 10240 B
    __shared__ short Bh[BN3 * LDP3];   // 20480 B
    __shared__ short Bl[BN3 * LDP3];   // 20480 B
    int tid = threadIdx.x;
    int lane = tid & 63;
    int wid = tid >> 6;   // 0..7
    int wm = wid & 1;
    int wn = wid >> 1;    // 0..3
    int bm = blockIdx.x * BM3;
    int bn = blockIdx.y * BN3;

    f32x4 acc[4][4] = {};

    int arow = tid >> 2, ak8 = (tid & 3) * 8;   // A: 4 thr/row, 8 floats each
    int brow = tid >> 1, bk16 = (tid & 1) * 16; // B: 2 thr/row, 16 shorts each
    int ga = bm + arow;
    bool aval = ga < N_NODES;

    for (int k0 = 0; k0 < CH; k0 += BK3) {
        // ---- stage A, splitting fp32 -> hi/lo bf16 in registers ----
        {
            const float* src = &A[(size_t)ga * CH + k0 + ak8];
            float4 f0 = aval ? *(const float4*)(src)     : make_float4(0.f, 0.f, 0.f, 0.f);
            float4 f1 = aval ? *(const float4*)(src + 4) : make_float4(0.f, 0.f, 0.f, 0.f);
            float fs[8] = {f0.x, f0.y, f0.z, f0.w, f1.x, f1.y, f1.z, f1.w};
            unsigned short h[8], l[8];
            #pragma unroll
            for (int j = 0; j < 8; ++j) {
                unsigned short hb = f2b(fs[j]);       // RTN hi
                union { unsigned int u; float ff; } t; t.u = (unsigned)hb << 16;
                float lo = fs[j] - t.ff;              // exact remainder
                h[j] = hb;
                l[j] = f2b(lo);
            }
            *(uint4*)&Ah[arow * LDP3 + ak8] =
                make_uint4(pack2(h[0], h[1]), pack2(h[2], h[3]), pack2(h[4], h[5]), pack2(h[6], h[7]));
            *(uint4*)&Al[arow * LDP3 + ak8] =
                make_uint4(pack2(l[0], l[1]), pack2(l[2], l[3]), pack2(l[4], l[5]), pack2(l[6], l[7]));
        }
        // ---- stage B hi/lo ----
        {
            const unsigned short* sh = &Wth[(size_t)(bn + brow) * CH + k0 + bk16];
            const unsigned short* sl = &Wtl[(size_t)(bn + brow) * CH + k0 + bk16];
            *(uint4*)&Bh[brow * LDP3 + bk16]     = *(const uint4*)sh;
            *(uint4*)&Bh[brow * LDP3 + bk16 + 8] = *(const uint4*)(sh + 8);
            *(uint4*)&Bl[brow * LDP3 + bk16]     = *(const uint4*)sl;
            *(uint4*)&Bl[brow * LDP3 + bk16 + 8] = *(const uint4*)(sl + 8);
        }
        __syncthreads();

        bf16x8 afh[4], afl[4], bfh[4], bfl[4];
        #pragma unroll
        for (int mt = 0; mt < 4; ++mt) {
            int off = (wm * 64 + mt * 16 + (lane & 15)) * LDP3 + (lane >> 4) * 8;
            afh[mt] = *(const bf16x8*)&Ah[off];
            afl[mt] = *(const bf16x8*)&Al[off];
        }
        #pragma unroll
        for (int nt = 0; nt < 4; ++nt) {
            int off = (wn * 64 + nt * 16 + (lane & 15)) * LDP3 + (lane >> 4) * 8;
            bfh[nt] = *(const bf16x8*)&Bh[off];
            bfl[nt] = *(const bf16x8*)&Bl[off];
        }
        #pragma unroll
        for (int mt = 0; mt < 4; ++mt)
            #pragma unroll
            for (int nt = 0; nt < 4; ++nt) {
                acc[mt][nt] = __builtin_amdgcn_mfma_f32_16x16x32_bf16(afh[mt], bfh[nt], acc[mt][nt], 0, 0, 0);
                acc[mt][nt] = __builtin_amdgcn_mfma_f32_16x16x32_bf16(afl[mt], bfh[nt], acc[mt][nt], 0, 0, 0);
                acc[mt][nt] = __builtin_amdgcn_mfma_f32_16x16x32_bf16(afh[mt], bfl[nt], acc[mt][nt], 0, 0, 0);
            }
        __syncthreads();
    }

    #pragma unroll
    for (int mt = 0; mt < 4; ++mt) {
        #pragma unroll
        for (int nt = 0; nt < 4; ++nt) {
            int col = bn + wn * 64 + nt * 16 + (lane & 15);
            float bv = bias[col];
            #pragma unroll
            for (int r = 0; r < 4; ++r) {
                int row = bm + wm * 64 + mt * 16 + (lane >> 4) * 4 + r;
                if (row < N_NODES) C[(size_t)row * CH + col] = acc[mt][nt][r] + bv;
            }
        }
    }
}

// ---------------- Softmax (+argmax + top-2 gap suspects), one wave per row ----------------
// bf16x3 logit error bound ~1.5e-5; flag gap < 2e-4 (6x margin).
// Expected suspects ~ 50000 * (2e-4 / 0.018) ~ 550 rows.

#define GAP_THR 2.0e-4f
#define SUSP_CAP 49999  // susp_rows lives in the 50000-int cursor region (1 int for count)

__global__ __launch_bounds__(256) void softmax_rows(const float* __restrict__ X, float* __restrict__ P,
                                                    float* __restrict__ preds,
                                                    int* __restrict__ susp_cnt,
                                                    int* __restrict__ susp_rows) {
    int row = blockIdx.x * 4 + (threadIdx.x >> 6);
    int lane = threadIdx.x & 63;
    if (row >= N_NODES) return;
    const float4* x4 = (const float4*)(X + (size_t)row * CH);
    float4 v0 = x4[lane];
    float4 v1 = x4[lane + 64];
    float vals[8] = {v0.x, v0.y, v0.z, v0.w, v1.x, v1.y, v1.z, v1.w};
    float m = vals[0];
    float m2 = -INFINITY;
    int mi = lane * 4;
    #pragma unroll
    for (int j = 1; j < 8; ++j) {
        int c = (j < 4) ? (lane * 4 + j) : (256 + lane * 4 + (j - 4));
        if (vals[j] > m) { m2 = m; m = vals[j]; mi = c; }
        else if (vals[j] > m2) { m2 = vals[j]; }
    }
    #pragma unroll
    for (int d = 32; d > 0; d >>= 1) {
        float om = __shfl_xor(m, d, 64);
        int oi = __shfl_xor(mi, d, 64);
        float om2 = __shfl_xor(m2, d, 64);
        if (om > m || (om == m && oi < mi)) {
            m2 = fmaxf(m, om2);
            m = om; mi = oi;
        } else {
            m2 = fmaxf(m2, om);
        }
    }
    float s = 0.f;
    float ex[8];
    #pragma unroll
    for (int j = 0; j < 8; ++j) { ex[j] = __expf(vals[j] - m); s += ex[j]; }
    #pragma unroll
    for (int d = 32; d > 0; d >>= 1) s += __shfl_xor(s, d, 64);
    float inv = 1.0f / s;
    float4 o0 = make_float4(ex[0] * inv, ex[1] * inv, ex[2] * inv, ex[3] * inv);
    float4 o1 = make_float4(ex[4] * inv, ex[5] * inv, ex[6] * inv, ex[7] * inv);
    float4* p4 = (float4*)(P + (size_t)row * CH);
    p4[lane] = o0;
    p4[lane + 64] = o1;
    if (preds != nullptr && lane == 0) {
        preds[row] = (float)mi;
        if (m - m2 < GAP_THR) {
            int p = atomicAdd(susp_cnt, 1);
            if (p < SUSP_CAP) susp_rows[p] = row;
        }
    }
}

// ---------------- exact fp32 argmax fixup for suspect rows ----------------
// For each suspect row: recompute logits = A_row(f32) @ W + bias in fp32, rewrite preds.

__global__ __launch_bounds__(256) void fix_preds(const float* __restrict__ A, const float* __restrict__ W,
                                                 const float* __restrict__ bias,
                                                 const int* __restrict__ susp_cnt,
                                                 const int* __restrict__ susp_rows,
                                                 float* __restrict__ preds) {
    __shared__ float rowbuf[8][512];
    __shared__ float rbest[8][4];
    __shared__ int ridx[8][4];
    int cnt = *susp_cnt;
    if (cnt > SUSP_CAP) cnt = SUSP_CAP;
    int tid = threadIdx.x, lane = tid & 63, wid = tid >> 6;
    for (int base = blockIdx.x * 8; base < cnt; base += gridDim.x * 8) {
        int nr = min(8, cnt - base);
        __syncthreads();  // protect rowbuf reuse across sweep iterations
        for (int r = 0; r < nr; ++r) {
            int row = susp_rows[base + r];
            if (tid < 128) ((float4*)rowbuf[r])[tid] = ((const float4*)&A[(size_t)row * 512])[tid];
        }
        __syncthreads();
        float best[8]; int bidx[8];
        #pragma unroll
        for (int r = 0; r < 8; ++r) { best[r] = -INFINITY; bidx[r] = 0; }
        for (int cc = 0; cc < 2; ++cc) {
            int c = cc * 256 + tid;
            float bv = bias[c];
            float s[8];
            #pragma unroll
            for (int r = 0; r < 8; ++r) s[r] = bv;
            #pragma unroll 8
            for (int k = 0; k < 512; ++k) {
                float w = W[(size_t)k * 512 + c];
                #pragma unroll
                for (int r = 0; r < 8; ++r) s[r] += rowbuf[r][k] * w;
            }
            #pragma unroll
            for (int r = 0; r < 8; ++r)
                if (s[r] > best[r]) { best[r] = s[r]; bidx[r] = c; }  // cc ascending: strict > keeps lower col on tie
        }
        #pragma unroll
        for (int r = 0; r < 8; ++r) {
            float b = best[r]; int i = bidx[r];
            #pragma unroll
            for (int d = 32; d > 0; d >>= 1) {
                float ob = __shfl_xor(b, d, 64);
                int oi = __shfl_xor(i, d, 64);
                if (ob > b || (ob == b && oi < i)) { b = ob; i = oi; }
            }
            if (lane == 0) { rbest[r][wid] = b; ridx[r][wid] = i; }
        }
        __syncthreads();
        if (tid < nr) {
            int r = tid;
            float b = rbest[r][0]; int i = ridx[r][0];
            #pragma unroll
            for (int w = 1; w < 4; ++w) {
                if (rbest[r][w] > b || (rbest[r][w] == b && ridx[r][w] < i)) { b = rbest[r][w]; i = ridx[r][w]; }
            }
            preds[susp_rows[base + r]] = (float)i;
        }
    }
}

// ---------------- launcher ----------------

extern "C" void kernel_launch(void* const* d_in, const int* in_sizes, int n_in,
                              void* d_out, int out_size, void* d_ws, size_t ws_size,
                              hipStream_t stream) {
    const float* x  = (const float*)d_in[0];
    const int*   e1 = (const int*)d_in[1];
    const int*   e2 = (const int*)d_in[2];
    const float* W1 = (const float*)d_in[3];
    const float* b1 = (const float*)d_in[4];
    const float* W2 = (const float*)d_in[5];
    const float* b2 = (const float*)d_in[6];

    float* out     = (float*)d_out;
    float* logits1 = out;
    float* logits2 = out + (size_t)N_NODES * CH;
    float* preds   = out + 2 * (size_t)N_NODES * CH;

    const size_t NEED = 109600016;
    if (ws_size < NEED) return;

    char* ws = (char*)d_ws;
    float* A      = (float*)(ws);                 // 102.4 MB fp32 scratch
    int*   cnt    = (int*)(ws + 102400000);
    int*   offs   = (int*)(ws + 102600000);
    int*   cursor = (int*)(ws + 102800016);
    float* dinv   = (float*)(ws + 103000016);
    int*   srcs   = (int*)(ws + 103200016);
    float* enorm  = (float*)(ws + 106400016);

    // conv2 bf16 scratch carved from regions free during conv2:
    unsigned short* xb  = (unsigned short*)logits1;                    // 51.2 MB in logits1 region
    unsigned short* Wtb = (unsigned short*)((char*)logits1 + 51200000);// 0.5 MB, also logits1 region
    unsigned short* h1b = (unsigned short*)A;                          // 51.2 MB
    unsigned short* h2b = (unsigned short*)((char*)A + 51200000);      // 51.2 MB

    // conv1 bf16x3 scratch, live only after conv1 propagation (srcs/enorm dead then):
    unsigned short* Wt1h = (unsigned short*)srcs;    // 0.5 MB in srcs region (3.2 MB)
    unsigned short* Wt1l = (unsigned short*)enorm;   // 0.5 MB in enorm region (3.2 MB)
    int* susp_cnt  = (int*)cursor;                   // cursor region dead after fill_csr
    int* susp_rows = (int*)cursor + 1;

    // ================= conv2 (bf16 path) first =================
    {
        hipMemsetAsync(cnt, 0, N_NODES * sizeof(int), stream);
        hipMemsetAsync(cursor, 0, N_NODES * sizeof(int), stream);
        count_col<<<(N_EDGES + 255) / 256, 256, 0, stream>>>(e2 + N_EDGES, cnt);
        scan_offsets<<<1, 1024, 0, stream>>>(cnt, offs, dinv);
        fill_csr<<<(N_EDGES + 255) / 256, 256, 0, stream>>>(e2, offs, cursor, dinv, srcs, enorm);

        convert_x_bf16<<<(N_NODES * CH / 8 + 255) / 256, 256, 0, stream>>>(x, xb);
        convert_w_t<<<(512 * 512) / 256, 256, 0, stream>>>(W2, Wtb);

        propagate_bf16<<<N_NODES / 2, 128, 0, stream>>>(xb, h1b, offs, srcs, enorm, dinv);
        propagate_bf16<<<N_NODES / 2, 128, 0, stream>>>(h1b, h2b, offs, srcs, enorm, dinv);

        dim3 g((N_NODES + BM2 - 1) / BM2, CH / BN2);
        gemm_bf16<<<g, 512, 0, stream>>>(h2b, Wtb, b2, logits2);
        softmax_rows<<<N_NODES / 4, 256, 0, stream>>>(logits2, logits2, nullptr, nullptr, nullptr);
    }

    // ================= conv1 (fp32 propagation + bf16x3 MFMA GEMM, argmax-exact via fixup) =================
    {
        hipMemsetAsync(cnt, 0, N_NODES * sizeof(int), stream);
        hipMemsetAsync(cursor, 0, N_NODES * sizeof(int), stream);
        count_col<<<(N_EDGES + 255) / 256, 256, 0, stream>>>(e1 + N_EDGES, cnt);
        scan_offsets<<<1, 1024, 0, stream>>>(cnt, offs, dinv);
        fill_csr<<<(N_EDGES + 255) / 256, 256, 0, stream>>>(e1, offs, cursor, dinv, srcs, enorm);

        propagate<<<N_NODES, 128, 0, stream>>>(x, logits1, offs, srcs, enorm, dinv);
        propagate<<<N_NODES, 128, 0, stream>>>(logits1, A, offs, srcs, enorm, dinv);

        // srcs/enorm now dead -> reuse for split W1; cursor dead -> suspect list
        convert_w_t_split<<<(512 * 512) / 256, 256, 0, stream>>>(W1, Wt1h, Wt1l);
        hipMemsetAsync(susp_cnt, 0, sizeof(int), stream);

        dim3 g((N_NODES + BM3 - 1) / BM3, CH / BN3);
        gemm_bf16x3<<<g, 512, 0, stream>>>(A, Wt1h, Wt1l, b1, logits1);
        softmax_rows<<<N_NODES / 4, 256, 0, stream>>>(logits1, logits1, preds, susp_cnt, susp_rows);
        fix_preds<<<400, 256, 0, stream>>>(A, W1, b1, susp_cnt, susp_rows, preds);
    }
}

// Round 5
// 1560.853 us; speedup vs baseline: 2.0731x; 1.0739x over previous
//
#include <hip/hip_runtime.h>
#include <hip/hip_bf16.h>
#include <cstdint>
#include <cstddef>

#define N_NODES 50000
#define N_EDGES 800000
#define CH 512
#define SCAN_NB 49  // ceil(50000/1024)

typedef __attribute__((ext_vector_type(8))) short bf16x8;
typedef __attribute__((ext_vector_type(4))) float f32x4;

__device__ inline unsigned short f2b(float f) {
    __hip_bfloat16 h = __float2bfloat16(f);
    return *(unsigned short*)&h;
}
__device__ inline float blo(unsigned int u) {  // low 16 bits as bf16 -> f32
    union { unsigned int i; float f; } v; v.i = u << 16; return v.f;
}
__device__ inline float bhi(unsigned int u) {  // high 16 bits as bf16 -> f32
    union { unsigned int i; float f; } v; v.i = u & 0xffff0000u; return v.f;
}
__device__ inline unsigned int pack2(unsigned short a, unsigned short b) {
    return (unsigned)a | ((unsigned)b << 16);
}

// ---------------- CSR build (both edge sets, parallel scan) ----------------

__global__ __launch_bounds__(256) void count_both(const int* __restrict__ e1, const int* __restrict__ e2,
                                                  int* __restrict__ cnt1, int* __restrict__ cnt2) {
    int t = blockIdx.x * 256 + threadIdx.x;
    if (t < N_EDGES) {
        atomicAdd(&cnt1[e1[N_EDGES + t]], 1);
    } else if (t < 2 * N_EDGES) {
        int e = t - N_EDGES;
        atomicAdd(&cnt2[e2[N_EDGES + e]], 1);
    }
}

// Stage 1: per-block (1024 items) local exclusive scan into offs; block totals into bsum.
__global__ __launch_bounds__(256) void scan_s1(const int* __restrict__ c1, const int* __restrict__ c2,
                                               int* __restrict__ o1, int* __restrict__ o2,
                                               int* __restrict__ bsum) {
    const int* cnt = blockIdx.y ? c2 : c1;
    int* offs = blockIdx.y ? o2 : o1;
    int* bs = bsum + blockIdx.y * 64;
    int b = blockIdx.x, tid = threadIdx.x;
    int lane = tid & 63, wid = tid >> 6;
    int i0 = b * 1024 + tid * 4;
    int v[4];
    #pragma unroll
    for (int j = 0; j < 4; ++j) { int i = i0 + j; v[j] = (i < N_NODES) ? cnt[i] : 0; }
    int tsum = v[0] + v[1] + v[2] + v[3];
    int incl = tsum;
    #pragma unroll
    for (int d = 1; d < 64; d <<= 1) {
        int t = __shfl_up(incl, d, 64);
        if (lane >= d) incl += t;
    }
    __shared__ int wsum[4];
    if (lane == 63) wsum[wid] = incl;
    __syncthreads();
    int wbase = 0;
    for (int w = 0; w < wid; ++w) wbase += wsum[w];
    int run = wbase + incl - tsum;  // exclusive prefix of this thread's first item
    #pragma unroll
    for (int j = 0; j < 4; ++j) { int i = i0 + j; if (i < N_NODES) offs[i] = run; run += v[j]; }
    if (tid == 255) bs[b] = wbase + incl;  // block total
}

// Stage 2: single wave scans the 49 block totals (exclusive, in place); writes offs[N] = grand total.
__global__ __launch_bounds__(64) void scan_s2(int* __restrict__ bsum,
                                              int* __restrict__ o1, int* __restrict__ o2) {
    int* bs = bsum + blockIdx.y * 64;
    int* offs = blockIdx.y ? o2 : o1;
    int t = threadIdx.x;
    int v = (t < SCAN_NB) ? bs[t] : 0;
    int incl = v;
    #pragma unroll
    for (int d = 1; d < 64; d <<= 1) {
        int u = __shfl_up(incl, d, 64);
        if (t >= d) incl += u;
    }
    if (t < SCAN_NB) bs[t] = incl - v;  // exclusive
    if (t == 63) offs[N_NODES] = incl;  // grand total (padding lanes added 0)
}

// Stage 3: add block prefixes; emit dinv; zero cursor.
__global__ __launch_bounds__(256) void scan_s3(const int* __restrict__ c1, const int* __restrict__ c2,
                                               int* __restrict__ o1, int* __restrict__ o2,
                                               float* __restrict__ d1, float* __restrict__ d2,
                                               int* __restrict__ cur1, int* __restrict__ cur2,
                                               const int* __restrict__ bsum) {
    const int* cnt = blockIdx.y ? c2 : c1;
    int* offs = blockIdx.y ? o2 : o1;
    float* dinv = blockIdx.y ? d2 : d1;
    int* cursor = blockIdx.y ? cur2 : cur1;
    int add = bsum[blockIdx.y * 64 + blockIdx.x];
    int i0 = blockIdx.x * 1024 + threadIdx.x * 4;
    #pragma unroll
    for (int j = 0; j < 4; ++j) {
        int i = i0 + j;
        if (i < N_NODES) {
            offs[i] += add;
            dinv[i] = rsqrtf((float)(cnt[i] + 1));  // +1 self loop
            cursor[i] = 0;
        }
    }
}

__global__ __launch_bounds__(256) void fill_both(const int* __restrict__ e1,
                                                 const int* __restrict__ offs1, int* __restrict__ cur1,
                                                 const float* __restrict__ dinv1,
                                                 int* __restrict__ srcs1, float* __restrict__ enorm1,
                                                 const int* __restrict__ e2,
                                                 const int* __restrict__ offs2, int* __restrict__ cur2,
                                                 const float* __restrict__ dinv2,
                                                 int* __restrict__ srcs2, float* __restrict__ enorm2) {
    int t = blockIdx.x * 256 + threadIdx.x;
    if (t < N_EDGES) {
        int r = e1[t];
        int c = e1[N_EDGES + t];
        int p = offs1[c] + atomicAdd(&cur1[c], 1);
        srcs1[p] = r;
        enorm1[p] = dinv1[r] * dinv1[c];
    } else if (t < 2 * N_EDGES) {
        int e = t - N_EDGES;
        int r = e2[e];
        int c = e2[N_EDGES + e];
        int p = offs2[c] + atomicAdd(&cur2[c], 1);
        srcs2[p] = r;
        enorm2[p] = dinv2[r] * dinv2[c];
    }
}

// ---------------- converters ----------------

__global__ __launch_bounds__(256) void convert_x_bf16(const float* __restrict__ x, unsigned short* __restrict__ xb) {
    int i8 = blockIdx.x * 256 + threadIdx.x;  // 8 floats per thread
    const float4* x4 = (const float4*)x;
    float4 a = x4[2 * i8], b = x4[2 * i8 + 1];
    unsigned int o[4];
    o[0] = pack2(f2b(a.x), f2b(a.y));
    o[1] = pack2(f2b(a.z), f2b(a.w));
    o[2] = pack2(f2b(b.x), f2b(b.y));
    o[3] = pack2(f2b(b.z), f2b(b.w));
    ((uint4*)xb)[i8] = make_uint4(o[0], o[1], o[2], o[3]);
}

// Wt[n][k] = bf16(W[k][n])
__global__ __launch_bounds__(256) void convert_w_t(const float* __restrict__ W, unsigned short* __restrict__ Wt) {
    int id = blockIdx.x * 256 + threadIdx.x;
    int k = id >> 9, n = id & 511;
    Wt[(size_t)n * 512 + k] = f2b(W[(size_t)k * 512 + n]);
}

// Split W into hi/lo bf16, transposed n-major: Wth[n][k] + Wtl[n][k] ~= W[k][n] (fp32)
__global__ __launch_bounds__(256) void convert_w_t_split(const float* __restrict__ W,
                                                         unsigned short* __restrict__ Wth,
                                                         unsigned short* __restrict__ Wtl) {
    int id = blockIdx.x * 256 + threadIdx.x;
    int k = id >> 9, n = id & 511;
    float f = W[(size_t)k * 512 + n];
    unsigned short hb = f2b(f);  // RTN
    union { unsigned int u; float ff; } t; t.u = (unsigned)hb << 16;
    float lo = f - t.ff;
    Wth[(size_t)n * 512 + k] = hb;
    Wtl[(size_t)n * 512 + k] = f2b(lo);
}

// ---------------- fp32 propagation (conv1): unroll-8 gather ----------------

__global__ __launch_bounds__(128) void propagate(const float* __restrict__ h, float* __restrict__ out,
                                                 const int* __restrict__ offs,
                                                 const int* __restrict__ srcs,
                                                 const float* __restrict__ enorm,
                                                 const float* __restrict__ dinv) {
    int node = blockIdx.x;
    int t = threadIdx.x;  // 128 threads * float4 = 512 channels
    const float4* h4 = (const float4*)h;
    float di = dinv[node];
    float w0 = di * di;
    float4 v = h4[(size_t)node * 128 + t];
    float4 acc = make_float4(v.x * w0, v.y * w0, v.z * w0, v.w * w0);
    int e0 = offs[node], e1 = offs[node + 1];
    int e = e0;
    int eu = e0 + ((e1 - e0) & ~7);
    for (; e < eu; e += 8) {
        int s[8]; float w[8];
        #pragma unroll
        for (int q = 0; q < 8; ++q) { s[q] = srcs[e + q]; w[q] = enorm[e + q]; }
        float4 u[8];
        #pragma unroll
        for (int q = 0; q < 8; ++q) u[q] = h4[(size_t)s[q] * 128 + t];
        #pragma unroll
        for (int q = 0; q < 8; ++q) {
            acc.x += u[q].x * w[q]; acc.y += u[q].y * w[q];
            acc.z += u[q].z * w[q]; acc.w += u[q].w * w[q];
        }
    }
    for (; e < e1; ++e) {
        int s = srcs[e];
        float w = enorm[e];
        float4 u = h4[(size_t)s * 128 + t];
        acc.x += u.x * w; acc.y += u.y * w; acc.z += u.z * w; acc.w += u.w * w;
    }
    ((float4*)out)[(size_t)node * 128 + t] = acc;
}

// ---------------- bf16 propagation (conv2): wave per node, fp32 accum, unroll-8 ----------------

__global__ __launch_bounds__(128) void propagate_bf16(const unsigned short* __restrict__ hb,
                                                      unsigned short* __restrict__ outb,
                                                      const int* __restrict__ offs,
                                                      const int* __restrict__ srcs,
                                                      const float* __restrict__ enorm,
                                                      const float* __restrict__ dinv) {
    int node = blockIdx.x * 2 + (threadIdx.x >> 6);
    int lane = threadIdx.x & 63;  // lane handles 8 channels (16 B)
    const uint4* h16 = (const uint4*)hb;  // 64 uint4 per row
    float di = dinv[node];
    float w0 = di * di;
    float acc[8];
    uint4 sv = h16[(size_t)node * 64 + lane];
    acc[0] = blo(sv.x) * w0; acc[1] = bhi(sv.x) * w0;
    acc[2] = blo(sv.y) * w0; acc[3] = bhi(sv.y) * w0;
    acc[4] = blo(sv.z) * w0; acc[5] = bhi(sv.z) * w0;
    acc[6] = blo(sv.w) * w0; acc[7] = bhi(sv.w) * w0;
    int e0 = offs[node], e1 = offs[node + 1];
    int e = e0;
    int eu = e0 + ((e1 - e0) & ~7);
    for (; e < eu; e += 8) {
        int s[8]; float w[8];
        #pragma unroll
        for (int q = 0; q < 8; ++q) { s[q] = srcs[e + q]; w[q] = enorm[e + q]; }
        uint4 u[8];
        #pragma unroll
        for (int q = 0; q < 8; ++q) u[q] = h16[(size_t)s[q] * 64 + lane];
        #pragma unroll
        for (int q = 0; q < 8; ++q) {
            acc[0] += blo(u[q].x) * w[q]; acc[1] += bhi(u[q].x) * w[q];
            acc[2] += blo(u[q].y) * w[q]; acc[3] += bhi(u[q].y) * w[q];
            acc[4] += blo(u[q].z) * w[q]; acc[5] += bhi(u[q].z) * w[q];
            acc[6] += blo(u[q].w) * w[q]; acc[7] += bhi(u[q].w) * w[q];
        }
    }
    for (; e < e1; ++e) {
        int s = srcs[e];
        float w = enorm[e];
        uint4 u = h16[(size_t)s * 64 + lane];
        acc[0] += blo(u.x) * w; acc[1] += bhi(u.x) * w;
        acc[2] += blo(u.y) * w; acc[3] += bhi(u.y) * w;
        acc[4] += blo(u.z) * w; acc[5] += bhi(u.z) * w;
        acc[6] += blo(u.w) * w; acc[7] += bhi(u.w) * w;
    }
    unsigned int o0 = pack2(f2b(acc[0]), f2b(acc[1]));
    unsigned int o1 = pack2(f2b(acc[2]), f2b(acc[3]));
    unsigned int o2 = pack2(f2b(acc[4]), f2b(acc[5]));
    unsigned int o3 = pack2(f2b(acc[6]), f2b(acc[7]));
    ((uint4*)outb)[(size_t)node * 64 + lane] = make_uint4(o0, o1, o2, o3);
}

// ---------------- bf16 MFMA GEMM (conv2): C[M,512] = Ab @ Wt^T + bias ----------------
// Block: 512 thr = 8 waves (2 row-halves x 4 col-quarters), tile BM2=128 x BN2=256, BK2=32.

#define BM2 128
#define BN2 256
#define BK2 32
#define LDP 40  // LDS row pitch in shorts (80 B -> 2-way bank aliasing only)

__global__ __launch_bounds__(512) void gemm_bf16(const unsigned short* __restrict__ Ab,
                                                 const unsigned short* __restrict__ Wt,
                                                 const float* __restrict__ bias,
                                                 float* __restrict__ C) {
    __shared__ short Alds[BM2 * LDP];   // 10240 B
    __shared__ short Blds[BN2 * LDP];   // 20480 B
    int tid = threadIdx.x;
    int lane = tid & 63;
    int wid = tid >> 6;   // 0..7
    int wm = wid & 1;     // 64-row half
    int wn = wid >> 1;    // 0..3 -> 64-col quarter
    int bm = blockIdx.x * BM2;
    int bn = blockIdx.y * BN2;

    f32x4 acc[4][4] = {};

    int arow = tid >> 2, ak8 = (tid & 3) * 8;   // A: 4 thr/row, 8 shorts each
    int brow = tid >> 1, bk16 = (tid & 1) * 16; // B: 2 thr/row, 16 shorts each
    int ga = bm + arow;
    bool aval = ga < N_NODES;

    for (int k0 = 0; k0 < CH; k0 += BK2) {
        {
            uint4 v = make_uint4(0u, 0u, 0u, 0u);
            if (aval) v = *(const uint4*)&Ab[(size_t)ga * CH + k0 + ak8];
            *(uint4*)&Alds[arow * LDP + ak8] = v;
        }
        {
            const unsigned short* s = &Wt[(size_t)(bn + brow) * CH + k0 + bk16];
            *(uint4*)&Blds[brow * LDP + bk16] = *(const uint4*)s;
            *(uint4*)&Blds[brow * LDP + bk16 + 8] = *(const uint4*)(s + 8);
        }
        __syncthreads();

        bf16x8 af[4], bf[4];
        #pragma unroll
        for (int mt = 0; mt < 4; ++mt)
            af[mt] = *(const bf16x8*)&Alds[(wm * 64 + mt * 16 + (lane & 15)) * LDP + (lane >> 4) * 8];
        #pragma unroll
        for (int nt = 0; nt < 4; ++nt)
            bf[nt] = *(const bf16x8*)&Blds[(wn * 64 + nt * 16 + (lane & 15)) * LDP + (lane >> 4) * 8];
        #pragma unroll
        for (int mt = 0; mt < 4; ++mt)
            #pragma unroll
            for (int nt = 0; nt < 4; ++nt)
                acc[mt][nt] = __builtin_amdgcn_mfma_f32_16x16x32_bf16(af[mt], bf[nt], acc[mt][nt], 0, 0, 0);
        __syncthreads();
    }

    #pragma unroll
    for (int mt = 0; mt < 4; ++mt) {
        #pragma unroll
        for (int nt = 0; nt < 4; ++nt) {
            int col = bn + wn * 64 + nt * 16 + (lane & 15);
            float bv = bias[col];
            #pragma unroll
            for (int r = 0; r < 4; ++r) {
                int row = bm + wm * 64 + mt * 16 + (lane >> 4) * 4 + r;
                if (row < N_NODES) C[(size_t)row * CH + col] = acc[mt][nt][r] + bv;
            }
        }
    }
}

// ---------------- bf16x3 split MFMA GEMM (conv1): C = A(f32) @ W + bias ----------------
// C ~= A_hi@W_hi + A_lo@W_hi + A_hi@W_lo   (error bound ~3*2^-18*||a||*||w|| ~ 1.5e-5)

#define BM3 128
#define BN3 256
#define BK3 32
#define LDP3 40

__global__ __launch_bounds__(512) void gemm_bf16x3(const float* __restrict__ A,
                                                   const unsigned short* __restrict__ Wth,
                                                   const unsigned short* __restrict__ Wtl,
                                                   const float* __restrict__ bias,
                                                   float* __restrict__ C) {
    __shared__ short Ah[BM3 * LDP3];   // 10240 B
    __shared__ short Al[BM3 * LDP3];   // 10240 B
    __shared__ short Bh[BN3 * LDP3];   // 20480 B
    __shared__ short Bl[BN3 * LDP3];   // 20480 B
    int tid = threadIdx.x;
    int lane = tid & 63;
    int wid = tid >> 6;   // 0..7
    int wm = wid & 1;
    int wn = wid >> 1;    // 0..3
    int bm = blockIdx.x * BM3;
    int bn = blockIdx.y * BN3;

    f32x4 acc[4][4] = {};

    int arow = tid >> 2, ak8 = (tid & 3) * 8;   // A: 4 thr/row, 8 floats each
    int brow = tid >> 1, bk16 = (tid & 1) * 16; // B: 2 thr/row, 16 shorts each
    int ga = bm + arow;
    bool aval = ga < N_NODES;

    for (int k0 = 0; k0 < CH; k0 += BK3) {
        {
            const float* src = &A[(size_t)ga * CH + k0 + ak8];
            float4 f0 = aval ? *(const float4*)(src)     : make_float4(0.f, 0.f, 0.f, 0.f);
            float4 f1 = aval ? *(const float4*)(src + 4) : make_float4(0.f, 0.f, 0.f, 0.f);
            float fs[8] = {f0.x, f0.y, f0.z, f0.w, f1.x, f1.y, f1.z, f1.w};
            unsigned short h[8], l[8];
            #pragma unroll
            for (int j = 0; j < 8; ++j) {
                unsigned short hb = f2b(fs[j]);       // RTN hi
                union { unsigned int u; float ff; } t; t.u = (unsigned)hb << 16;
                float lo = fs[j] - t.ff;              // exact remainder
                h[j] = hb;
                l[j] = f2b(lo);
            }
            *(uint4*)&Ah[arow * LDP3 + ak8] =
                make_uint4(pack2(h[0], h[1]), pack2(h[2], h[3]), pack2(h[4], h[5]), pack2(h[6], h[7]));
            *(uint4*)&Al[arow * LDP3 + ak8] =
                make_uint4(pack2(l[0], l[1]), pack2(l[2], l[3]), pack2(l[4], l[5]), pack2(l[6], l[7]));
        }
        {
            const unsigned short* sh = &Wth[(size_t)(bn + brow) * CH + k0 + bk16];
            const unsigned short* sl = &Wtl[(size_t)(bn + brow) * CH + k0 + bk16];
            *(uint4*)&Bh[brow * LDP3 + bk16]     = *(const uint4*)sh;
            *(uint4*)&Bh[brow * LDP3 + bk16 + 8] = *(const uint4*)(sh + 8);
            *(uint4*)&Bl[brow * LDP3 + bk16]     = *(const uint4*)sl;
            *(uint4*)&Bl[brow * LDP3 + bk16 + 8] = *(const uint4*)(sl + 8);
        }
        __syncthreads();

        bf16x8 afh[4], afl[4], bfh[4], bfl[4];
        #pragma unroll
        for (int mt = 0; mt < 4; ++mt) {
            int off = (wm * 64 + mt * 16 + (lane & 15)) * LDP3 + (lane >> 4) * 8;
            afh[mt] = *(const bf16x8*)&Ah[off];
            afl[mt] = *(const bf16x8*)&Al[off];
        }
        #pragma unroll
        for (int nt = 0; nt < 4; ++nt) {
            int off = (wn * 64 + nt * 16 + (lane & 15)) * LDP3 + (lane >> 4) * 8;
            bfh[nt] = *(const bf16x8*)&Bh[off];
            bfl[nt] = *(const bf16x8*)&Bl[off];
        }
        #pragma unroll
        for (int mt = 0; mt < 4; ++mt)
            #pragma unroll
            for (int nt = 0; nt < 4; ++nt) {
                acc[mt][nt] = __builtin_amdgcn_mfma_f32_16x16x32_bf16(afh[mt], bfh[nt], acc[mt][nt], 0, 0, 0);
                acc[mt][nt] = __builtin_amdgcn_mfma_f32_16x16x32_bf16(afl[mt], bfh[nt], acc[mt][nt], 0, 0, 0);
                acc[mt][nt] = __builtin_amdgcn_mfma_f32_16x16x32_bf16(afh[mt], bfl[nt], acc[mt][nt], 0, 0, 0);
            }
        __syncthreads();
    }

    #pragma unroll
    for (int mt = 0; mt < 4; ++mt) {
        #pragma unroll
        for (int nt = 0; nt < 4; ++nt) {
            int col = bn + wn * 64 + nt * 16 + (lane & 15);
            float bv = bias[col];
            #pragma unroll
            for (int r = 0; r < 4; ++r) {
                int row = bm + wm * 64 + mt * 16 + (lane >> 4) * 4 + r;
                if (row < N_NODES) C[(size_t)row * CH + col] = acc[mt][nt][r] + bv;
            }
        }
    }
}

// ---------------- Softmax (+argmax + top-2 gap suspects), one wave per row ----------------

#define GAP_THR 2.0e-4f
#define SUSP_CAP 49999  // susp_rows lives in the 50000-int cursor region (1 int for count)

__global__ __launch_bounds__(256) void softmax_rows(const float* __restrict__ X, float* __restrict__ P,
                                                    float* __restrict__ preds,
                                                    int* __restrict__ susp_cnt,
                                                    int* __restrict__ susp_rows) {
    int row = blockIdx.x * 4 + (threadIdx.x >> 6);
    int lane = threadIdx.x & 63;
    if (row >= N_NODES) return;
    const float4* x4 = (const float4*)(X + (size_t)row * CH);
    float4 v0 = x4[lane];
    float4 v1 = x4[lane + 64];
    float vals[8] = {v0.x, v0.y, v0.z, v0.w, v1.x, v1.y, v1.z, v1.w};
    float m = vals[0];
    float m2 = -INFINITY;
    int mi = lane * 4;
    #pragma unroll
    for (int j = 1; j < 8; ++j) {
        int c = (j < 4) ? (lane * 4 + j) : (256 + lane * 4 + (j - 4));
        if (vals[j] > m) { m2 = m; m = vals[j]; mi = c; }
        else if (vals[j] > m2) { m2 = vals[j]; }
    }
    #pragma unroll
    for (int d = 32; d > 0; d >>= 1) {
        float om = __shfl_xor(m, d, 64);
        int oi = __shfl_xor(mi, d, 64);
        float om2 = __shfl_xor(m2, d, 64);
        if (om > m || (om == m && oi < mi)) {
            m2 = fmaxf(m, om2);
            m = om; mi = oi;
        } else {
            m2 = fmaxf(m2, om);
        }
    }
    float s = 0.f;
    float ex[8];
    #pragma unroll
    for (int j = 0; j < 8; ++j) { ex[j] = __expf(vals[j] - m); s += ex[j]; }
    #pragma unroll
    for (int d = 32; d > 0; d >>= 1) s += __shfl_xor(s, d, 64);
    float inv = 1.0f / s;
    float4 o0 = make_float4(ex[0] * inv, ex[1] * inv, ex[2] * inv, ex[3] * inv);
    float4 o1 = make_float4(ex[4] * inv, ex[5] * inv, ex[6] * inv, ex[7] * inv);
    float4* p4 = (float4*)(P + (size_t)row * CH);
    p4[lane] = o0;
    p4[lane + 64] = o1;
    if (preds != nullptr && lane == 0) {
        preds[row] = (float)mi;
        if (m - m2 < GAP_THR) {
            int p = atomicAdd(susp_cnt, 1);
            if (p < SUSP_CAP) susp_rows[p] = row;
        }
    }
}

// ---------------- exact fp32 argmax fixup for suspect rows ----------------

__global__ __launch_bounds__(256) void fix_preds(const float* __restrict__ A, const float* __restrict__ W,
                                                 const float* __restrict__ bias,
                                                 const int* __restrict__ susp_cnt,
                                                 const int* __restrict__ susp_rows,
                                                 float* __restrict__ preds) {
    __shared__ float rowbuf[8][512];
    __shared__ float rbest[8][4];
    __shared__ int ridx[8][4];
    int cnt = *susp_cnt;
    if (cnt > SUSP_CAP) cnt = SUSP_CAP;
    int tid = threadIdx.x, lane = tid & 63, wid = tid >> 6;
    for (int base = blockIdx.x * 8; base < cnt; base += gridDim.x * 8) {
        int nr = min(8, cnt - base);
        __syncthreads();  // protect rowbuf reuse across sweep iterations
        for (int r = 0; r < nr; ++r) {
            int row = susp_rows[base + r];
            if (tid < 128) ((float4*)rowbuf[r])[tid] = ((const float4*)&A[(size_t)row * 512])[tid];
        }
        __syncthreads();
        float best[8]; int bidx[8];
        #pragma unroll
        for (int r = 0; r < 8; ++r) { best[r] = -INFINITY; bidx[r] = 0; }
        for (int cc = 0; cc < 2; ++cc) {
            int c = cc * 256 + tid;
            float bv = bias[c];
            float s[8];
            #pragma unroll
            for (int r = 0; r < 8; ++r) s[r] = bv;
            #pragma unroll 8
            for (int k = 0; k < 512; ++k) {
                float w = W[(size_t)k * 512 + c];
                #pragma unroll
                for (int r = 0; r < 8; ++r) s[r] += rowbuf[r][k] * w;
            }
            #pragma unroll
            for (int r = 0; r < 8; ++r)
                if (s[r] > best[r]) { best[r] = s[r]; bidx[r] = c; }  // cc ascending: strict > keeps lower col on tie
        }
        #pragma unroll
        for (int r = 0; r < 8; ++r) {
            float b = best[r]; int i = bidx[r];
            #pragma unroll
            for (int d = 32; d > 0; d >>= 1) {
                float ob = __shfl_xor(b, d, 64);
                int oi = __shfl_xor(i, d, 64);
                if (ob > b || (ob == b && oi < i)) { b = ob; i = oi; }
            }
            if (lane == 0) { rbest[r][wid] = b; ridx[r][wid] = i; }
        }
        __syncthreads();
        if (tid < nr) {
            int r = tid;
            float b = rbest[r][0]; int i = ridx[r][0];
            #pragma unroll
            for (int w = 1; w < 4; ++w) {
                if (rbest[r][w] > b || (rbest[r][w] == b && ridx[r][w] < i)) { b = rbest[r][w]; i = ridx[r][w]; }
            }
            preds[susp_rows[base + r]] = (float)i;
        }
    }
}

// ---------------- launcher ----------------

extern "C" void kernel_launch(void* const* d_in, const int* in_sizes, int n_in,
                              void* d_out, int out_size, void* d_ws, size_t ws_size,
                              hipStream_t stream) {
    const float* x  = (const float*)d_in[0];
    const int*   e1 = (const int*)d_in[1];
    const int*   e2 = (const int*)d_in[2];
    const float* W1 = (const float*)d_in[3];
    const float* b1 = (const float*)d_in[4];
    const float* W2 = (const float*)d_in[5];
    const float* b2 = (const float*)d_in[6];

    float* out     = (float*)d_out;
    float* logits1 = out;
    float* logits2 = out + (size_t)N_NODES * CH;
    float* preds   = out + 2 * (size_t)N_NODES * CH;

    const size_t NEED = 109600016;
    if (ws_size < NEED) return;

    char* ws = (char*)d_ws;
    // CSR1 (conv1) in workspace:
    float* A       = (float*)(ws);                 // 102.4 MB fp32 scratch (h1b/h2b during conv2)
    int*   cnt1    = (int*)(ws + 102400000);
    int*   offs1   = (int*)(ws + 102600000);
    int*   cursor1 = (int*)(ws + 102800016);
    float* dinv1   = (float*)(ws + 103000016);
    int*   srcs1   = (int*)(ws + 103200016);
    float* enorm1  = (float*)(ws + 106400016);

    // CSR2 (conv2) carved from logits2 output region (dead until gemm_bf16 writes it):
    char* L2 = (char*)logits2;
    int*   cnt2    = (int*)(L2);
    int*   offs2   = (int*)(L2 + 200000);
    int*   cursor2 = (int*)(L2 + 400016);
    float* dinv2   = (float*)(L2 + 600016);
    int*   srcs2   = (int*)(L2 + 800016);
    float* enorm2  = (float*)(L2 + 4000016);
    int*   bsum    = (int*)(L2 + 7200016);   // 2 x 64 ints

    // conv2 bf16 scratch carved from regions free during conv2:
    unsigned short* xb  = (unsigned short*)logits1;                    // 51.2 MB in logits1 region
    unsigned short* Wtb = (unsigned short*)((char*)logits1 + 51200000);// 0.5 MB, also logits1 region
    unsigned short* h1b = (unsigned short*)A;                          // 51.2 MB
    unsigned short* h2b = (unsigned short*)((char*)A + 51200000);      // 51.2 MB

    // conv1 bf16x3 scratch, live only after conv1 propagation (srcs1/enorm1 dead then):
    unsigned short* Wt1h = (unsigned short*)srcs1;   // 0.5 MB in srcs1 region (3.2 MB)
    unsigned short* Wt1l = (unsigned short*)enorm1;  // 0.5 MB in enorm1 region (3.2 MB)
    int* susp_cnt  = (int*)cursor1;                  // cursor1 region dead after fill
    int* susp_rows = (int*)cursor1 + 1;

    // ================= build both CSRs (parallel scan, fused kernels) =================
    {
        hipMemsetAsync(cnt1, 0, N_NODES * sizeof(int), stream);
        hipMemsetAsync(cnt2, 0, N_NODES * sizeof(int), stream);
        count_both<<<(2 * N_EDGES + 255) / 256, 256, 0, stream>>>(e1, e2, cnt1, cnt2);
        scan_s1<<<dim3(SCAN_NB, 2), 256, 0, stream>>>(cnt1, cnt2, offs1, offs2, bsum);
        scan_s2<<<dim3(1, 2), 64, 0, stream>>>(bsum, offs1, offs2);
        scan_s3<<<dim3(SCAN_NB, 2), 256, 0, stream>>>(cnt1, cnt2, offs1, offs2,
                                                      dinv1, dinv2, cursor1, cursor2, bsum);
        fill_both<<<(2 * N_EDGES + 255) / 256, 256, 0, stream>>>(
            e1, offs1, cursor1, dinv1, srcs1, enorm1,
            e2, offs2, cursor2, dinv2, srcs2, enorm2);
    }

    // ================= conv2 (bf16 path) =================
    {
        convert_x_bf16<<<(N_NODES * CH / 8 + 255) / 256, 256, 0, stream>>>(x, xb);
        convert_w_t<<<(512 * 512) / 256, 256, 0, stream>>>(W2, Wtb);

        propagate_bf16<<<N_NODES / 2, 128, 0, stream>>>(xb, h1b, offs2, srcs2, enorm2, dinv2);
        propagate_bf16<<<N_NODES / 2, 128, 0, stream>>>(h1b, h2b, offs2, srcs2, enorm2, dinv2);

        dim3 g((N_NODES + BM2 - 1) / BM2, CH / BN2);
        gemm_bf16<<<g, 512, 0, stream>>>(h2b, Wtb, b2, logits2);   // overwrites CSR2 (dead now)
        softmax_rows<<<N_NODES / 4, 256, 0, stream>>>(logits2, logits2, nullptr, nullptr, nullptr);
    }

    // ================= conv1 (fp32 propagation + bf16x3 MFMA GEMM, argmax-exact via fixup) =================
    {
        propagate<<<N_NODES, 128, 0, stream>>>(x, logits1, offs1, srcs1, enorm1, dinv1);
        propagate<<<N_NODES, 128, 0, stream>>>(logits1, A, offs1, srcs1, enorm1, dinv1);

        // srcs1/enorm1 now dead -> reuse for split W1; cursor1 dead -> suspect list
        convert_w_t_split<<<(512 * 512) / 256, 256, 0, stream>>>(W1, Wt1h, Wt1l);
        hipMemsetAsync(susp_cnt, 0, sizeof(int), stream);

        dim3 g((N_NODES + BM3 - 1) / BM3, CH / BN3);
        gemm_bf16x3<<<g, 512, 0, stream>>>(A, Wt1h, Wt1l, b1, logits1);
        softmax_rows<<<N_NODES / 4, 256, 0, stream>>>(logits1, logits1, preds, susp_cnt, susp_rows);
        fix_preds<<<400, 256, 0, stream>>>(A, W1, b1, susp_cnt, susp_rows, preds);
    }
}

// Round 6
// 1511.610 us; speedup vs baseline: 2.1406x; 1.0326x over previous
//
#include <hip/hip_runtime.h>
#include <hip/hip_bf16.h>
#include <cstdint>
#include <cstddef>

#define N_NODES 50000
#define N_EDGES 800000
#define CH 512
#define SCAN_NB 49  // ceil(50000/1024)

typedef __attribute__((ext_vector_type(8))) short bf16x8;
typedef __attribute__((ext_vector_type(4))) float f32x4;

__device__ inline unsigned short f2b(float f) {
    __hip_bfloat16 h = __float2bfloat16(f);
    return *(unsigned short*)&h;
}
__device__ inline float blo(unsigned int u) {  // low 16 bits as bf16 -> f32
    union { unsigned int i; float f; } v; v.i = u << 16; return v.f;
}
__device__ inline float bhi(unsigned int u) {  // high 16 bits as bf16 -> f32
    union { unsigned int i; float f; } v; v.i = u & 0xffff0000u; return v.f;
}
__device__ inline unsigned int pack2(unsigned short a, unsigned short b) {
    return (unsigned)a | ((unsigned)b << 16);
}

// ---------------- CSR build (both edge sets, parallel scan) ----------------

__global__ __launch_bounds__(256) void count_both(const int* __restrict__ e1, const int* __restrict__ e2,
                                                  int* __restrict__ cnt1, int* __restrict__ cnt2) {
    int t = blockIdx.x * 256 + threadIdx.x;
    if (t < N_EDGES) {
        atomicAdd(&cnt1[e1[N_EDGES + t]], 1);
    } else if (t < 2 * N_EDGES) {
        int e = t - N_EDGES;
        atomicAdd(&cnt2[e2[N_EDGES + e]], 1);
    }
}

// Stage 1: per-block (1024 items) local exclusive scan into offs; block totals into bsum.
__global__ __launch_bounds__(256) void scan_s1(const int* __restrict__ c1, const int* __restrict__ c2,
                                               int* __restrict__ o1, int* __restrict__ o2,
                                               int* __restrict__ bsum) {
    const int* cnt = blockIdx.y ? c2 : c1;
    int* offs = blockIdx.y ? o2 : o1;
    int* bs = bsum + blockIdx.y * 64;
    int b = blockIdx.x, tid = threadIdx.x;
    int lane = tid & 63, wid = tid >> 6;
    int i0 = b * 1024 + tid * 4;
    int v[4];
    #pragma unroll
    for (int j = 0; j < 4; ++j) { int i = i0 + j; v[j] = (i < N_NODES) ? cnt[i] : 0; }
    int tsum = v[0] + v[1] + v[2] + v[3];
    int incl = tsum;
    #pragma unroll
    for (int d = 1; d < 64; d <<= 1) {
        int t = __shfl_up(incl, d, 64);
        if (lane >= d) incl += t;
    }
    __shared__ int wsum[4];
    if (lane == 63) wsum[wid] = incl;
    __syncthreads();
    int wbase = 0;
    for (int w = 0; w < wid; ++w) wbase += wsum[w];
    int run = wbase + incl - tsum;  // exclusive prefix of this thread's first item
    #pragma unroll
    for (int j = 0; j < 4; ++j) { int i = i0 + j; if (i < N_NODES) offs[i] = run; run += v[j]; }
    if (tid == 255) bs[b] = wbase + incl;  // block total
}

// Stage 2: single wave scans the 49 block totals (exclusive, in place); writes offs[N] = grand total.
__global__ __launch_bounds__(64) void scan_s2(int* __restrict__ bsum,
                                              int* __restrict__ o1, int* __restrict__ o2) {
    int* bs = bsum + blockIdx.y * 64;
    int* offs = blockIdx.y ? o2 : o1;
    int t = threadIdx.x;
    int v = (t < SCAN_NB) ? bs[t] : 0;
    int incl = v;
    #pragma unroll
    for (int d = 1; d < 64; d <<= 1) {
        int u = __shfl_up(incl, d, 64);
        if (t >= d) incl += u;
    }
    if (t < SCAN_NB) bs[t] = incl - v;  // exclusive
    if (t == 63) offs[N_NODES] = incl;  // grand total (padding lanes added 0)
}

// Stage 3: add block prefixes; emit dinv; zero cursor.
__global__ __launch_bounds__(256) void scan_s3(const int* __restrict__ c1, const int* __restrict__ c2,
                                               int* __restrict__ o1, int* __restrict__ o2,
                                               float* __restrict__ d1, float* __restrict__ d2,
                                               int* __restrict__ cur1, int* __restrict__ cur2,
                                               const int* __restrict__ bsum) {
    const int* cnt = blockIdx.y ? c2 : c1;
    int* offs = blockIdx.y ? o2 : o1;
    float* dinv = blockIdx.y ? d2 : d1;
    int* cursor = blockIdx.y ? cur2 : cur1;
    int add = bsum[blockIdx.y * 64 + blockIdx.x];
    int i0 = blockIdx.x * 1024 + threadIdx.x * 4;
    #pragma unroll
    for (int j = 0; j < 4; ++j) {
        int i = i0 + j;
        if (i < N_NODES) {
            offs[i] += add;
            dinv[i] = rsqrtf((float)(cnt[i] + 1));  // +1 self loop
            cursor[i] = 0;
        }
    }
}

__global__ __launch_bounds__(256) void fill_both(const int* __restrict__ e1,
                                                 const int* __restrict__ offs1, int* __restrict__ cur1,
                                                 const float* __restrict__ dinv1,
                                                 int* __restrict__ srcs1, float* __restrict__ enorm1,
                                                 const int* __restrict__ e2,
                                                 const int* __restrict__ offs2, int* __restrict__ cur2,
                                                 const float* __restrict__ dinv2,
                                                 int* __restrict__ srcs2, float* __restrict__ enorm2) {
    int t = blockIdx.x * 256 + threadIdx.x;
    if (t < N_EDGES) {
        int r = e1[t];
        int c = e1[N_EDGES + t];
        int p = offs1[c] + atomicAdd(&cur1[c], 1);
        srcs1[p] = r;
        enorm1[p] = dinv1[r] * dinv1[c];
    } else if (t < 2 * N_EDGES) {
        int e = t - N_EDGES;
        int r = e2[e];
        int c = e2[N_EDGES + e];
        int p = offs2[c] + atomicAdd(&cur2[c], 1);
        srcs2[p] = r;
        enorm2[p] = dinv2[r] * dinv2[c];
    }
}

// ---------------- converters ----------------

__global__ __launch_bounds__(256) void convert_x_bf16(const float* __restrict__ x, unsigned short* __restrict__ xb) {
    int i8 = blockIdx.x * 256 + threadIdx.x;  // 8 floats per thread
    const float4* x4 = (const float4*)x;
    float4 a = x4[2 * i8], b = x4[2 * i8 + 1];
    unsigned int o[4];
    o[0] = pack2(f2b(a.x), f2b(a.y));
    o[1] = pack2(f2b(a.z), f2b(a.w));
    o[2] = pack2(f2b(b.x), f2b(b.y));
    o[3] = pack2(f2b(b.z), f2b(b.w));
    ((uint4*)xb)[i8] = make_uint4(o[0], o[1], o[2], o[3]);
}

// Wt[n][k] = bf16(W[k][n])
__global__ __launch_bounds__(256) void convert_w_t(const float* __restrict__ W, unsigned short* __restrict__ Wt) {
    int id = blockIdx.x * 256 + threadIdx.x;
    int k = id >> 9, n = id & 511;
    Wt[(size_t)n * 512 + k] = f2b(W[(size_t)k * 512 + n]);
}

// Split W into hi/lo bf16, transposed n-major: Wth[n][k] + Wtl[n][k] ~= W[k][n] (fp32)
__global__ __launch_bounds__(256) void convert_w_t_split(const float* __restrict__ W,
                                                         unsigned short* __restrict__ Wth,
                                                         unsigned short* __restrict__ Wtl) {
    int id = blockIdx.x * 256 + threadIdx.x;
    int k = id >> 9, n = id & 511;
    float f = W[(size_t)k * 512 + n];
    unsigned short hb = f2b(f);  // RTN
    union { unsigned int u; float ff; } t; t.u = (unsigned)hb << 16;
    float lo = f - t.ff;
    Wth[(size_t)n * 512 + k] = hb;
    Wtl[(size_t)n * 512 + k] = f2b(lo);
}

// ---------------- fp32 propagation body (conv1): unroll-8 gather, 128 threads per node ----------------

__device__ inline void prop_node(const float* __restrict__ h, float* __restrict__ out,
                                 const int* __restrict__ offs, const int* __restrict__ srcs,
                                 const float* __restrict__ enorm, const float* __restrict__ dinv,
                                 int node, int t) {
    const float4* h4 = (const float4*)h;
    float di = dinv[node];
    float w0 = di * di;
    float4 v = h4[(size_t)node * 128 + t];
    float4 acc = make_float4(v.x * w0, v.y * w0, v.z * w0, v.w * w0);
    int e0 = offs[node], e1 = offs[node + 1];
    int e = e0;
    int eu = e0 + ((e1 - e0) & ~7);
    for (; e < eu; e += 8) {
        int s[8]; float w[8];
        #pragma unroll
        for (int q = 0; q < 8; ++q) { s[q] = srcs[e + q]; w[q] = enorm[e + q]; }
        float4 u[8];
        #pragma unroll
        for (int q = 0; q < 8; ++q) u[q] = h4[(size_t)s[q] * 128 + t];
        #pragma unroll
        for (int q = 0; q < 8; ++q) {
            acc.x += u[q].x * w[q]; acc.y += u[q].y * w[q];
            acc.z += u[q].z * w[q]; acc.w += u[q].w * w[q];
        }
    }
    for (; e < e1; ++e) {
        int s = srcs[e];
        float w = enorm[e];
        float4 u = h4[(size_t)s * 128 + t];
        acc.x += u.x * w; acc.y += u.y * w; acc.z += u.z * w; acc.w += u.w * w;
    }
    ((float4*)out)[(size_t)node * 128 + t] = acc;
}

// ---------------- bf16 propagation (conv2): wave per node, fp32 accum, unroll-8 ----------------

__global__ __launch_bounds__(128) void propagate_bf16(const unsigned short* __restrict__ hb,
                                                      unsigned short* __restrict__ outb,
                                                      const int* __restrict__ offs,
                                                      const int* __restrict__ srcs,
                                                      const float* __restrict__ enorm,
                                                      const float* __restrict__ dinv) {
    int node = blockIdx.x * 2 + (threadIdx.x >> 6);
    int lane = threadIdx.x & 63;  // lane handles 8 channels (16 B)
    const uint4* h16 = (const uint4*)hb;  // 64 uint4 per row
    float di = dinv[node];
    float w0 = di * di;
    float acc[8];
    uint4 sv = h16[(size_t)node * 64 + lane];
    acc[0] = blo(sv.x) * w0; acc[1] = bhi(sv.x) * w0;
    acc[2] = blo(sv.y) * w0; acc[3] = bhi(sv.y) * w0;
    acc[4] = blo(sv.z) * w0; acc[5] = bhi(sv.z) * w0;
    acc[6] = blo(sv.w) * w0; acc[7] = bhi(sv.w) * w0;
    int e0 = offs[node], e1 = offs[node + 1];
    int e = e0;
    int eu = e0 + ((e1 - e0) & ~7);
    for (; e < eu; e += 8) {
        int s[8]; float w[8];
        #pragma unroll
        for (int q = 0; q < 8; ++q) { s[q] = srcs[e + q]; w[q] = enorm[e + q]; }
        uint4 u[8];
        #pragma unroll
        for (int q = 0; q < 8; ++q) u[q] = h16[(size_t)s[q] * 64 + lane];
        #pragma unroll
        for (int q = 0; q < 8; ++q) {
            acc[0] += blo(u[q].x) * w[q]; acc[1] += bhi(u[q].x) * w[q];
            acc[2] += blo(u[q].y) * w[q]; acc[3] += bhi(u[q].y) * w[q];
            acc[4] += blo(u[q].z) * w[q]; acc[5] += bhi(u[q].z) * w[q];
            acc[6] += blo(u[q].w) * w[q]; acc[7] += bhi(u[q].w) * w[q];
        }
    }
    for (; e < e1; ++e) {
        int s = srcs[e];
        float w = enorm[e];
        uint4 u = h16[(size_t)s * 64 + lane];
        acc[0] += blo(u.x) * w; acc[1] += bhi(u.x) * w;
        acc[2] += blo(u.y) * w; acc[3] += bhi(u.y) * w;
        acc[4] += blo(u.z) * w; acc[5] += bhi(u.z) * w;
        acc[6] += blo(u.w) * w; acc[7] += bhi(u.w) * w;
    }
    unsigned int o0 = pack2(f2b(acc[0]), f2b(acc[1]));
    unsigned int o1 = pack2(f2b(acc[2]), f2b(acc[3]));
    unsigned int o2 = pack2(f2b(acc[4]), f2b(acc[5]));
    unsigned int o3 = pack2(f2b(acc[6]), f2b(acc[7]));
    ((uint4*)outb)[(size_t)node * 64 + lane] = make_uint4(o0, o1, o2, o3);
}

// ---------------- FUSED A: gemm_bf16 (conv2) || propagate hop1 (conv1) ----------------
// Blocks [0, 782): GEMM C[M,512] = Ab @ Wt^T + bias, tile 128x256, 8 waves.
// Blocks [782, 13282): fp32 propagate, 4 nodes/block (128 thr each).

#define BM2 128
#define BN2 256
#define BK2 32
#define LDP 40  // LDS row pitch in shorts (80 B -> 2-way bank aliasing only)
#define GEMM2_GX 391  // ceil(50000/128)
#define GEMM2_BLOCKS (GEMM2_GX * 2)
#define PROP_BLOCKS 12500  // 50000 / 4

__global__ __launch_bounds__(512) void fused_gemm2_prop1(
        const unsigned short* __restrict__ Ab, const unsigned short* __restrict__ Wt,
        const float* __restrict__ bias, float* __restrict__ C,
        const float* __restrict__ hx, float* __restrict__ pout,
        const int* __restrict__ offs, const int* __restrict__ srcs,
        const float* __restrict__ enorm, const float* __restrict__ dinv) {
    __shared__ short Alds[BM2 * LDP];   // 10240 B
    __shared__ short Blds[BN2 * LDP];   // 20480 B
    int tid = threadIdx.x;
    if (blockIdx.x >= GEMM2_BLOCKS) {
        int node = (blockIdx.x - GEMM2_BLOCKS) * 4 + (tid >> 7);
        prop_node(hx, pout, offs, srcs, enorm, dinv, node, tid & 127);
        return;
    }
    int lane = tid & 63;
    int wid = tid >> 6;   // 0..7
    int wm = wid & 1;     // 64-row half
    int wn = wid >> 1;    // 0..3 -> 64-col quarter
    int bm = (blockIdx.x % GEMM2_GX) * BM2;
    int bn = (blockIdx.x / GEMM2_GX) * BN2;

    f32x4 acc[4][4] = {};

    int arow = tid >> 2, ak8 = (tid & 3) * 8;   // A: 4 thr/row, 8 shorts each
    int brow = tid >> 1, bk16 = (tid & 1) * 16; // B: 2 thr/row, 16 shorts each
    int ga = bm + arow;
    bool aval = ga < N_NODES;

    for (int k0 = 0; k0 < CH; k0 += BK2) {
        {
            uint4 v = make_uint4(0u, 0u, 0u, 0u);
            if (aval) v = *(const uint4*)&Ab[(size_t)ga * CH + k0 + ak8];
            *(uint4*)&Alds[arow * LDP + ak8] = v;
        }
        {
            const unsigned short* s = &Wt[(size_t)(bn + brow) * CH + k0 + bk16];
            *(uint4*)&Blds[brow * LDP + bk16] = *(const uint4*)s;
            *(uint4*)&Blds[brow * LDP + bk16 + 8] = *(const uint4*)(s + 8);
        }
        __syncthreads();

        bf16x8 af[4], bf[4];
        #pragma unroll
        for (int mt = 0; mt < 4; ++mt)
            af[mt] = *(const bf16x8*)&Alds[(wm * 64 + mt * 16 + (lane & 15)) * LDP + (lane >> 4) * 8];
        #pragma unroll
        for (int nt = 0; nt < 4; ++nt)
            bf[nt] = *(const bf16x8*)&Blds[(wn * 64 + nt * 16 + (lane & 15)) * LDP + (lane >> 4) * 8];
        #pragma unroll
        for (int mt = 0; mt < 4; ++mt)
            #pragma unroll
            for (int nt = 0; nt < 4; ++nt)
                acc[mt][nt] = __builtin_amdgcn_mfma_f32_16x16x32_bf16(af[mt], bf[nt], acc[mt][nt], 0, 0, 0);
        __syncthreads();
    }

    #pragma unroll
    for (int mt = 0; mt < 4; ++mt) {
        #pragma unroll
        for (int nt = 0; nt < 4; ++nt) {
            int col = bn + wn * 64 + nt * 16 + (lane & 15);
            float bv = bias[col];
            #pragma unroll
            for (int r = 0; r < 4; ++r) {
                int row = bm + wm * 64 + mt * 16 + (lane >> 4) * 4 + r;
                if (row < N_NODES) C[(size_t)row * CH + col] = acc[mt][nt][r] + bv;
            }
        }
    }
}

// ---------------- FUSED B: softmax (conv2, no preds) || propagate hop2 (conv1) ----------------
// Blocks [0, 6250): softmax, 8 rows/block (one wave per row).
// Blocks [6250, 18750): fp32 propagate, 4 nodes/block.

#define SM2_BLOCKS 6250  // 50000 / 8

__global__ __launch_bounds__(512) void fused_sm2_prop2(
        float* __restrict__ X,
        const float* __restrict__ hin, float* __restrict__ aout,
        const int* __restrict__ offs, const int* __restrict__ srcs,
        const float* __restrict__ enorm, const float* __restrict__ dinv) {
    int tid = threadIdx.x;
    if (blockIdx.x >= SM2_BLOCKS) {
        int node = (blockIdx.x - SM2_BLOCKS) * 4 + (tid >> 7);
        prop_node(hin, aout, offs, srcs, enorm, dinv, node, tid & 127);
        return;
    }
    int row = blockIdx.x * 8 + (tid >> 6);
    int lane = tid & 63;
    const float4* x4 = (const float4*)(X + (size_t)row * CH);
    float4 v0 = x4[lane];
    float4 v1 = x4[lane + 64];
    float vals[8] = {v0.x, v0.y, v0.z, v0.w, v1.x, v1.y, v1.z, v1.w};
    float m = vals[0];
    #pragma unroll
    for (int j = 1; j < 8; ++j) m = fmaxf(m, vals[j]);
    #pragma unroll
    for (int d = 32; d > 0; d >>= 1) m = fmaxf(m, __shfl_xor(m, d, 64));
    float s = 0.f;
    float ex[8];
    #pragma unroll
    for (int j = 0; j < 8; ++j) { ex[j] = __expf(vals[j] - m); s += ex[j]; }
    #pragma unroll
    for (int d = 32; d > 0; d >>= 1) s += __shfl_xor(s, d, 64);
    float inv = 1.0f / s;
    float4 o0 = make_float4(ex[0] * inv, ex[1] * inv, ex[2] * inv, ex[3] * inv);
    float4 o1 = make_float4(ex[4] * inv, ex[5] * inv, ex[6] * inv, ex[7] * inv);
    float4* p4 = (float4*)(X + (size_t)row * CH);
    p4[lane] = o0;
    p4[lane + 64] = o1;
}

// ---------------- bf16x3 split MFMA GEMM (conv1): C = A(f32) @ W + bias ----------------
// C ~= A_hi@W_hi + A_lo@W_hi + A_hi@W_lo   (error bound ~3*2^-18*||a||*||w|| ~ 1.5e-5)

#define BM3 128
#define BN3 256
#define BK3 32
#define LDP3 40

__global__ __launch_bounds__(512) void gemm_bf16x3(const float* __restrict__ A,
                                                   const unsigned short* __restrict__ Wth,
                                                   const unsigned short* __restrict__ Wtl,
                                                   const float* __restrict__ bias,
                                                   float* __restrict__ C) {
    __shared__ short Ah[BM3 * LDP3];   // 10240 B
    __shared__ short Al[BM3 * LDP3];   // 10240 B
    __shared__ short Bh[BN3 * LDP3];   // 20480 B
    __shared__ short Bl[BN3 * LDP3];   // 20480 B
    int tid = threadIdx.x;
    int lane = tid & 63;
    int wid = tid >> 6;   // 0..7
    int wm = wid & 1;
    int wn = wid >> 1;    // 0..3
    int bm = blockIdx.x * BM3;
    int bn = blockIdx.y * BN3;

    f32x4 acc[4][4] = {};

    int arow = tid >> 2, ak8 = (tid & 3) * 8;   // A: 4 thr/row, 8 floats each
    int brow = tid >> 1, bk16 = (tid & 1) * 16; // B: 2 thr/row, 16 shorts each
    int ga = bm + arow;
    bool aval = ga < N_NODES;

    for (int k0 = 0; k0 < CH; k0 += BK3) {
        {
            const float* src = &A[(size_t)ga * CH + k0 + ak8];
            float4 f0 = aval ? *(const float4*)(src)     : make_float4(0.f, 0.f, 0.f, 0.f);
            float4 f1 = aval ? *(const float4*)(src + 4) : make_float4(0.f, 0.f, 0.f, 0.f);
            float fs[8] = {f0.x, f0.y, f0.z, f0.w, f1.x, f1.y, f1.z, f1.w};
            unsigned short h[8], l[8];
            #pragma unroll
            for (int j = 0; j < 8; ++j) {
                unsigned short hb = f2b(fs[j]);       // RTN hi
                union { unsigned int u; float ff; } t; t.u = (unsigned)hb << 16;
                float lo = fs[j] - t.ff;              // exact remainder
                h[j] = hb;
                l[j] = f2b(lo);
            }
            *(uint4*)&Ah[arow * LDP3 + ak8] =
                make_uint4(pack2(h[0], h[1]), pack2(h[2], h[3]), pack2(h[4], h[5]), pack2(h[6], h[7]));
            *(uint4*)&Al[arow * LDP3 + ak8] =
                make_uint4(pack2(l[0], l[1]), pack2(l[2], l[3]), pack2(l[4], l[5]), pack2(l[6], l[7]));
        }
        {
            const unsigned short* sh = &Wth[(size_t)(bn + brow) * CH + k0 + bk16];
            const unsigned short* sl = &Wtl[(size_t)(bn + brow) * CH + k0 + bk16];
            *(uint4*)&Bh[brow * LDP3 + bk16]     = *(const uint4*)sh;
            *(uint4*)&Bh[brow * LDP3 + bk16 + 8] = *(const uint4*)(sh + 8);
            *(uint4*)&Bl[brow * LDP3 + bk16]     = *(const uint4*)sl;
            *(uint4*)&Bl[brow * LDP3 + bk16 + 8] = *(const uint4*)(sl + 8);
        }
        __syncthreads();

        bf16x8 afh[4], afl[4], bfh[4], bfl[4];
        #pragma unroll
        for (int mt = 0; mt < 4; ++mt) {
            int off = (wm * 64 + mt * 16 + (lane & 15)) * LDP3 + (lane >> 4) * 8;
            afh[mt] = *(const bf16x8*)&Ah[off];
            afl[mt] = *(const bf16x8*)&Al[off];
        }
        #pragma unroll
        for (int nt = 0; nt < 4; ++nt) {
            int off = (wn * 64 + nt * 16 + (lane & 15)) * LDP3 + (lane >> 4) * 8;
            bfh[nt] = *(const bf16x8*)&Bh[off];
            bfl[nt] = *(const bf16x8*)&Bl[off];
        }
        #pragma unroll
        for (int mt = 0; mt < 4; ++mt)
            #pragma unroll
            for (int nt = 0; nt < 4; ++nt) {
                acc[mt][nt] = __builtin_amdgcn_mfma_f32_16x16x32_bf16(afh[mt], bfh[nt], acc[mt][nt], 0, 0, 0);
                acc[mt][nt] = __builtin_amdgcn_mfma_f32_16x16x32_bf16(afl[mt], bfh[nt], acc[mt][nt], 0, 0, 0);
                acc[mt][nt] = __builtin_amdgcn_mfma_f32_16x16x32_bf16(afh[mt], bfl[nt], acc[mt][nt], 0, 0, 0);
            }
        __syncthreads();
    }

    #pragma unroll
    for (int mt = 0; mt < 4; ++mt) {
        #pragma unroll
        for (int nt = 0; nt < 4; ++nt) {
            int col = bn + wn * 64 + nt * 16 + (lane & 15);
            float bv = bias[col];
            #pragma unroll
            for (int r = 0; r < 4; ++r) {
                int row = bm + wm * 64 + mt * 16 + (lane >> 4) * 4 + r;
                if (row < N_NODES) C[(size_t)row * CH + col] = acc[mt][nt][r] + bv;
            }
        }
    }
}

// ---------------- Softmax (+argmax + top-2 gap suspects), one wave per row ----------------

#define GAP_THR 2.0e-4f
#define SUSP_CAP 49999  // susp_rows lives in the 50000-int cursor region (1 int for count)

__global__ __launch_bounds__(256) void softmax_rows(const float* __restrict__ X, float* __restrict__ P,
                                                    float* __restrict__ preds,
                                                    int* __restrict__ susp_cnt,
                                                    int* __restrict__ susp_rows) {
    int row = blockIdx.x * 4 + (threadIdx.x >> 6);
    int lane = threadIdx.x & 63;
    if (row >= N_NODES) return;
    const float4* x4 = (const float4*)(X + (size_t)row * CH);
    float4 v0 = x4[lane];
    float4 v1 = x4[lane + 64];
    float vals[8] = {v0.x, v0.y, v0.z, v0.w, v1.x, v1.y, v1.z, v1.w};
    float m = vals[0];
    float m2 = -INFINITY;
    int mi = lane * 4;
    #pragma unroll
    for (int j = 1; j < 8; ++j) {
        int c = (j < 4) ? (lane * 4 + j) : (256 + lane * 4 + (j - 4));
        if (vals[j] > m) { m2 = m; m = vals[j]; mi = c; }
        else if (vals[j] > m2) { m2 = vals[j]; }
    }
    #pragma unroll
    for (int d = 32; d > 0; d >>= 1) {
        float om = __shfl_xor(m, d, 64);
        int oi = __shfl_xor(mi, d, 64);
        float om2 = __shfl_xor(m2, d, 64);
        if (om > m || (om == m && oi < mi)) {
            m2 = fmaxf(m, om2);
            m = om; mi = oi;
        } else {
            m2 = fmaxf(m2, om);
        }
    }
    float s = 0.f;
    float ex[8];
    #pragma unroll
    for (int j = 0; j < 8; ++j) { ex[j] = __expf(vals[j] - m); s += ex[j]; }
    #pragma unroll
    for (int d = 32; d > 0; d >>= 1) s += __shfl_xor(s, d, 64);
    float inv = 1.0f / s;
    float4 o0 = make_float4(ex[0] * inv, ex[1] * inv, ex[2] * inv, ex[3] * inv);
    float4 o1 = make_float4(ex[4] * inv, ex[5] * inv, ex[6] * inv, ex[7] * inv);
    float4* p4 = (float4*)(P + (size_t)row * CH);
    p4[lane] = o0;
    p4[lane + 64] = o1;
    if (preds != nullptr && lane == 0) {
        preds[row] = (float)mi;
        if (m - m2 < GAP_THR) {
            int p = atomicAdd(susp_cnt, 1);
            if (p < SUSP_CAP) susp_rows[p] = row;
        }
    }
}

// ---------------- exact fp32 argmax fixup for suspect rows ----------------

__global__ __launch_bounds__(256) void fix_preds(const float* __restrict__ A, const float* __restrict__ W,
                                                 const float* __restrict__ bias,
                                                 const int* __restrict__ susp_cnt,
                                                 const int* __restrict__ susp_rows,
                                                 float* __restrict__ preds) {
    __shared__ float rowbuf[8][512];
    __shared__ float rbest[8][4];
    __shared__ int ridx[8][4];
    int cnt = *susp_cnt;
    if (cnt > SUSP_CAP) cnt = SUSP_CAP;
    int tid = threadIdx.x, lane = tid & 63, wid = tid >> 6;
    for (int base = blockIdx.x * 8; base < cnt; base += gridDim.x * 8) {
        int nr = min(8, cnt - base);
        __syncthreads();  // protect rowbuf reuse across sweep iterations
        for (int r = 0; r < nr; ++r) {
            int row = susp_rows[base + r];
            if (tid < 128) ((float4*)rowbuf[r])[tid] = ((const float4*)&A[(size_t)row * 512])[tid];
        }
        __syncthreads();
        float best[8]; int bidx[8];
        #pragma unroll
        for (int r = 0; r < 8; ++r) { best[r] = -INFINITY; bidx[r] = 0; }
        for (int cc = 0; cc < 2; ++cc) {
            int c = cc * 256 + tid;
            float bv = bias[c];
            float s[8];
            #pragma unroll
            for (int r = 0; r < 8; ++r) s[r] = bv;
            #pragma unroll 8
            for (int k = 0; k < 512; ++k) {
                float w = W[(size_t)k * 512 + c];
                #pragma unroll
                for (int r = 0; r < 8; ++r) s[r] += rowbuf[r][k] * w;
            }
            #pragma unroll
            for (int r = 0; r < 8; ++r)
                if (s[r] > best[r]) { best[r] = s[r]; bidx[r] = c; }  // cc ascending: strict > keeps lower col on tie
        }
        #pragma unroll
        for (int r = 0; r < 8; ++r) {
            float b = best[r]; int i = bidx[r];
            #pragma unroll
            for (int d = 32; d > 0; d >>= 1) {
                float ob = __shfl_xor(b, d, 64);
                int oi = __shfl_xor(i, d, 64);
                if (ob > b || (ob == b && oi < i)) { b = ob; i = oi; }
            }
            if (lane == 0) { rbest[r][wid] = b; ridx[r][wid] = i; }
        }
        __syncthreads();
        if (tid < nr) {
            int r = tid;
            float b = rbest[r][0]; int i = ridx[r][0];
            #pragma unroll
            for (int w = 1; w < 4; ++w) {
                if (rbest[r][w] > b || (rbest[r][w] == b && ridx[r][w] < i)) { b = rbest[r][w]; i = ridx[r][w]; }
            }
            preds[susp_rows[base + r]] = (float)i;
        }
    }
}

// ---------------- launcher ----------------

extern "C" void kernel_launch(void* const* d_in, const int* in_sizes, int n_in,
                              void* d_out, int out_size, void* d_ws, size_t ws_size,
                              hipStream_t stream) {
    const float* x  = (const float*)d_in[0];
    const int*   e1 = (const int*)d_in[1];
    const int*   e2 = (const int*)d_in[2];
    const float* W1 = (const float*)d_in[3];
    const float* b1 = (const float*)d_in[4];
    const float* W2 = (const float*)d_in[5];
    const float* b2 = (const float*)d_in[6];

    float* out     = (float*)d_out;
    float* logits1 = out;
    float* logits2 = out + (size_t)N_NODES * CH;
    float* preds   = out + 2 * (size_t)N_NODES * CH;

    const size_t NEED = 109600016;
    if (ws_size < NEED) return;

    char* ws = (char*)d_ws;
    // CSR1 (conv1) in workspace:
    float* A       = (float*)(ws);                 // 102.4 MB fp32 scratch (h1b/h2b during conv2)
    int*   cnt1    = (int*)(ws + 102400000);
    int*   offs1   = (int*)(ws + 102600000);
    int*   cursor1 = (int*)(ws + 102800016);
    float* dinv1   = (float*)(ws + 103000016);
    int*   srcs1   = (int*)(ws + 103200016);
    float* enorm1  = (float*)(ws + 106400016);

    // CSR2 (conv2) carved from logits2 output region (dead until FUSED A's gemm writes it):
    char* L2 = (char*)logits2;
    int*   cnt2    = (int*)(L2);
    int*   offs2   = (int*)(L2 + 200000);
    int*   cursor2 = (int*)(L2 + 400016);
    float* dinv2   = (float*)(L2 + 600016);
    int*   srcs2   = (int*)(L2 + 800016);
    float* enorm2  = (float*)(L2 + 4000016);
    int*   bsum    = (int*)(L2 + 7200016);   // 2 x 64 ints

    // conv2 bf16 scratch:
    unsigned short* xb  = (unsigned short*)logits1;              // 51.2 MB in logits1 (dead before FUSED A writes logits1)
    unsigned short* h1b = (unsigned short*)A;                    // 51.2 MB
    unsigned short* h2b = (unsigned short*)((char*)A + 51200000);// 51.2 MB
    unsigned short* Wtb = (unsigned short*)A;                    // 0.5 MB in h1b zone (h1b dead after pbf16 hop2;
                                                                 //  Wtb consumed by FUSED A's gemm, before FUSED B writes A)

    // conv1 bf16x3 scratch, live only after conv1 propagation (srcs1/enorm1 dead then):
    unsigned short* Wt1h = (unsigned short*)srcs1;   // 0.5 MB in srcs1 region (3.2 MB)
    unsigned short* Wt1l = (unsigned short*)enorm1;  // 0.5 MB in enorm1 region (3.2 MB)
    int* susp_cnt  = (int*)cursor1;                  // cursor1 region dead after fill
    int* susp_rows = (int*)cursor1 + 1;

    // ================= build both CSRs (parallel scan, fused kernels) =================
    hipMemsetAsync(cnt1, 0, N_NODES * sizeof(int), stream);
    hipMemsetAsync(cnt2, 0, N_NODES * sizeof(int), stream);
    count_both<<<(2 * N_EDGES + 255) / 256, 256, 0, stream>>>(e1, e2, cnt1, cnt2);
    scan_s1<<<dim3(SCAN_NB, 2), 256, 0, stream>>>(cnt1, cnt2, offs1, offs2, bsum);
    scan_s2<<<dim3(1, 2), 64, 0, stream>>>(bsum, offs1, offs2);
    scan_s3<<<dim3(SCAN_NB, 2), 256, 0, stream>>>(cnt1, cnt2, offs1, offs2,
                                                  dinv1, dinv2, cursor1, cursor2, bsum);
    fill_both<<<(2 * N_EDGES + 255) / 256, 256, 0, stream>>>(
        e1, offs1, cursor1, dinv1, srcs1, enorm1,
        e2, offs2, cursor2, dinv2, srcs2, enorm2);

    // ================= conv2 propagation (bf16) =================
    convert_x_bf16<<<(N_NODES * CH / 8 + 255) / 256, 256, 0, stream>>>(x, xb);
    propagate_bf16<<<N_NODES / 2, 128, 0, stream>>>(xb, h1b, offs2, srcs2, enorm2, dinv2);
    propagate_bf16<<<N_NODES / 2, 128, 0, stream>>>(h1b, h2b, offs2, srcs2, enorm2, dinv2);

    // h1b dead now -> stage Wtb into its zone
    convert_w_t<<<(512 * 512) / 256, 256, 0, stream>>>(W2, Wtb);

    // ================= FUSED A: conv2 GEMM || conv1 propagate hop1 =================
    fused_gemm2_prop1<<<GEMM2_BLOCKS + PROP_BLOCKS, 512, 0, stream>>>(
        h2b, Wtb, b2, logits2,
        x, logits1, offs1, srcs1, enorm1, dinv1);

    // ================= FUSED B: conv2 softmax || conv1 propagate hop2 =================
    fused_sm2_prop2<<<SM2_BLOCKS + PROP_BLOCKS, 512, 0, stream>>>(
        logits2,
        logits1, A, offs1, srcs1, enorm1, dinv1);

    // ================= conv1 GEMM (bf16x3) + softmax + exact fixup =================
    // srcs1/enorm1 now dead -> reuse for split W1; cursor1 dead -> suspect list
    convert_w_t_split<<<(512 * 512) / 256, 256, 0, stream>>>(W1, Wt1h, Wt1l);
    hipMemsetAsync(susp_cnt, 0, sizeof(int), stream);

    dim3 g((N_NODES + BM3 - 1) / BM3, CH / BN3);
    gemm_bf16x3<<<g, 512, 0, stream>>>(A, Wt1h, Wt1l, b1, logits1);
    softmax_rows<<<N_NODES / 4, 256, 0, stream>>>(logits1, logits1, preds, susp_cnt, susp_rows);
    fix_preds<<<400, 256, 0, stream>>>(A, W1, b1, susp_cnt, susp_rows, preds);
}